// Round 1
// baseline (513.793 us; speedup 1.0000x reference)
//
#include <hip/hip_runtime.h>
#include <math.h>

// Problem constants
#define N_TOK 32768      // 32*32*32 tokens
#define NE    1024       // codebook size
#define DIM   256        // code dim
#define LDZ   68         // padded LDS stride (68*4B = 272B, multiple of 16B)

// d_out layout (fp32 elements):
//  [0]                loss
//  [1 .. 8388609)     z_q_st (32,256,32,32)
//  [8388609]          perplexity
//  [8388610 .. +33554432)  one_hot (32768,1024)
//  [41943042 .. +32768)    indices (as float)
#define OFF_ZQ   1u
#define OFF_PPL  8388609u
#define OFF_OH   8388610u
#define OFF_IDX  41943042u

__global__ void vq_init(float* wsf) { wsf[0] = 0.0f; }

// ---------------------------------------------------------------------------
// Argmin kernel: each block handles 64 consecutive token rows, scans all 1024
// codes in chunks of 64 staged in LDS. Distances follow the reference formula
// (zn + en) - 2*dot, fp32, first-min tie-break.
// ---------------------------------------------------------------------------
__global__ __launch_bounds__(256) void vq_argmin(const float* __restrict__ z,
                                                 const float* __restrict__ ew,
                                                 float* __restrict__ out_idx)
{
    __shared__ float zt[DIM * LDZ];   // [d][r] transposed z tile, 69.6 KB
    __shared__ float et[DIM * LDZ];   // [d][k] transposed e chunk, 69.6 KB
    __shared__ float zn[64];
    __shared__ float en[64];

    const int t    = threadIdx.x;
    const int r0   = blockIdx.x << 6;       // global row base (64 rows/block)
    const int bimg = r0 >> 10;              // batch image (1024 tokens per image)
    const int hw0  = r0 & 1023;

    // stage z tile: global layout z[b][d][hw]; rows r0..r0+63 share bimg
    const float* zb = z + (size_t)bimg * (DIM * 1024) + hw0;
#pragma unroll 4
    for (int i = 0; i < 64; ++i) {
        int l = (i << 8) + t;
        int d = l >> 6;
        int r = l & 63;
        zt[d * LDZ + r] = zb[d * 1024 + r];   // coalesced read, 2-way LDS write (free)
    }
    __syncthreads();

    // per-row squared norms
    if (t < 64) {
        float s = 0.0f;
#pragma unroll 8
        for (int d = 0; d < DIM; ++d) { float v = zt[d * LDZ + t]; s = fmaf(v, v, s); }
        zn[t] = s;
    }
    __syncthreads();

    const int rt = t & 15;    // row group: rows 4*rt .. 4*rt+3
    const int ct = t >> 4;    // code group: codes 4*ct .. 4*ct+3 (within chunk)

    float best0 = 1e30f, best1 = 1e30f, best2 = 1e30f, best3 = 1e30f;
    int   bix0 = 0, bix1 = 0, bix2 = 0, bix3 = 0;

    for (int kc = 0; kc < 16; ++kc) {
        const int k0 = kc << 6;
        const float* eb = ew + (size_t)k0 * DIM;
        // stage e chunk transposed: thread t owns d=t, iterates codes
#pragma unroll 4
        for (int i = 0; i < 64; ++i) {
            et[t * LDZ + i] = eb[i * DIM + t];   // coalesced global read
        }
        __syncthreads();

        if (t < 64) {
            float s = 0.0f;
#pragma unroll 8
            for (int d = 0; d < DIM; ++d) { float v = et[d * LDZ + t]; s = fmaf(v, v, s); }
            en[t] = s;
        }
        __syncthreads();

        // 4x4 register-tile dot products over d
        float4 a0 = make_float4(0.f, 0.f, 0.f, 0.f);
        float4 a1 = make_float4(0.f, 0.f, 0.f, 0.f);
        float4 a2 = make_float4(0.f, 0.f, 0.f, 0.f);
        float4 a3 = make_float4(0.f, 0.f, 0.f, 0.f);
        const float* zp = zt + (rt << 2);
        const float* ep = et + (ct << 2);
#pragma unroll 4
        for (int d = 0; d < DIM; ++d) {
            float4 z4 = *reinterpret_cast<const float4*>(zp + d * LDZ);
            float4 e4 = *reinterpret_cast<const float4*>(ep + d * LDZ);
            a0.x = fmaf(z4.x, e4.x, a0.x); a0.y = fmaf(z4.x, e4.y, a0.y);
            a0.z = fmaf(z4.x, e4.z, a0.z); a0.w = fmaf(z4.x, e4.w, a0.w);
            a1.x = fmaf(z4.y, e4.x, a1.x); a1.y = fmaf(z4.y, e4.y, a1.y);
            a1.z = fmaf(z4.y, e4.z, a1.z); a1.w = fmaf(z4.y, e4.w, a1.w);
            a2.x = fmaf(z4.z, e4.x, a2.x); a2.y = fmaf(z4.z, e4.y, a2.y);
            a2.z = fmaf(z4.z, e4.z, a2.z); a2.w = fmaf(z4.z, e4.w, a2.w);
            a3.x = fmaf(z4.w, e4.x, a3.x); a3.y = fmaf(z4.w, e4.y, a3.y);
            a3.z = fmaf(z4.w, e4.z, a3.z); a3.w = fmaf(z4.w, e4.w, a3.w);
        }

        // epilogue: dist = (zn + en) - 2*dot  (2*dot is exact: same as reference)
        const float4 en4 = *reinterpret_cast<const float4*>(en + (ct << 2));
        const int kb = k0 + (ct << 2);
        {
            float znj = zn[(rt << 2) + 0];
            float d0 = (znj + en4.x) - 2.0f * a0.x;
            float d1 = (znj + en4.y) - 2.0f * a0.y;
            float d2 = (znj + en4.z) - 2.0f * a0.z;
            float d3 = (znj + en4.w) - 2.0f * a0.w;
            if (d0 < best0) { best0 = d0; bix0 = kb + 0; }
            if (d1 < best0) { best0 = d1; bix0 = kb + 1; }
            if (d2 < best0) { best0 = d2; bix0 = kb + 2; }
            if (d3 < best0) { best0 = d3; bix0 = kb + 3; }
        }
        {
            float znj = zn[(rt << 2) + 1];
            float d0 = (znj + en4.x) - 2.0f * a1.x;
            float d1 = (znj + en4.y) - 2.0f * a1.y;
            float d2 = (znj + en4.z) - 2.0f * a1.z;
            float d3 = (znj + en4.w) - 2.0f * a1.w;
            if (d0 < best1) { best1 = d0; bix1 = kb + 0; }
            if (d1 < best1) { best1 = d1; bix1 = kb + 1; }
            if (d2 < best1) { best1 = d2; bix1 = kb + 2; }
            if (d3 < best1) { best1 = d3; bix1 = kb + 3; }
        }
        {
            float znj = zn[(rt << 2) + 2];
            float d0 = (znj + en4.x) - 2.0f * a2.x;
            float d1 = (znj + en4.y) - 2.0f * a2.y;
            float d2 = (znj + en4.z) - 2.0f * a2.z;
            float d3 = (znj + en4.w) - 2.0f * a2.w;
            if (d0 < best2) { best2 = d0; bix2 = kb + 0; }
            if (d1 < best2) { best2 = d1; bix2 = kb + 1; }
            if (d2 < best2) { best2 = d2; bix2 = kb + 2; }
            if (d3 < best2) { best2 = d3; bix2 = kb + 3; }
        }
        {
            float znj = zn[(rt << 2) + 3];
            float d0 = (znj + en4.x) - 2.0f * a3.x;
            float d1 = (znj + en4.y) - 2.0f * a3.y;
            float d2 = (znj + en4.z) - 2.0f * a3.z;
            float d3 = (znj + en4.w) - 2.0f * a3.w;
            if (d0 < best3) { best3 = d0; bix3 = kb + 0; }
            if (d1 < best3) { best3 = d1; bix3 = kb + 1; }
            if (d2 < best3) { best3 = d2; bix3 = kb + 2; }
            if (d3 < best3) { best3 = d3; bix3 = kb + 3; }
        }
        __syncthreads();   // before next chunk overwrites et
    }

    // cross-thread reduce: 16 ct-groups per row, tie-break on lower code index
    float* rd = et;                       // [64][16] floats
    int*   ri = reinterpret_cast<int*>(et + 64 * 16);
    rd[((rt << 2) + 0) * 16 + ct] = best0; ri[((rt << 2) + 0) * 16 + ct] = bix0;
    rd[((rt << 2) + 1) * 16 + ct] = best1; ri[((rt << 2) + 1) * 16 + ct] = bix1;
    rd[((rt << 2) + 2) * 16 + ct] = best2; ri[((rt << 2) + 2) * 16 + ct] = bix2;
    rd[((rt << 2) + 3) * 16 + ct] = best3; ri[((rt << 2) + 3) * 16 + ct] = bix3;
    __syncthreads();
    if (t < 64) {
        float bd = rd[t * 16];
        int   bi = ri[t * 16];
        for (int c = 1; c < 16; ++c) {
            float dc = rd[t * 16 + c];
            int   ic = ri[t * 16 + c];
            if (dc < bd || (dc == bd && ic < bi)) { bd = dc; bi = ic; }
        }
        out_idx[r0 + t] = (float)bi;
    }
}

// ---------------------------------------------------------------------------
// one_hot: 33.5M floats. Region is only 8B-aligned -> float2 stores.
// ---------------------------------------------------------------------------
__global__ __launch_bounds__(256) void vq_onehot(const float* __restrict__ idxf,
                                                 float* __restrict__ oh)
{
    const unsigned stride = gridDim.x * blockDim.x;
    const unsigned total2 = N_TOK * (NE / 2);   // 16777216 float2
    for (unsigned o2 = blockIdx.x * blockDim.x + threadIdx.x; o2 < total2; o2 += stride) {
        unsigned n = o2 >> 7;               // 128 float2 per row
        int k = (int)((o2 & 127u) << 1);
        int idx = (int)idxf[n];
        float2 v;
        v.x = (k == idx) ? 1.0f : 0.0f;
        v.y = (k + 1 == idx) ? 1.0f : 0.0f;
        reinterpret_cast<float2*>(oh)[o2] = v;
    }
}

// ---------------------------------------------------------------------------
// z_q gather + SSE accumulation. z_q region is only 4B-aligned -> scalar ops.
// Forward value of z_q_st == z_q (z + (z_q - z) differs only by ~1e-7).
// ---------------------------------------------------------------------------
__global__ __launch_bounds__(256) void vq_gather(const float* __restrict__ z,
                                                 const float* __restrict__ ew,
                                                 const float* __restrict__ idxf,
                                                 float* __restrict__ zq,
                                                 float* __restrict__ sse)
{
    float part = 0.0f;
    const unsigned stride = gridDim.x * blockDim.x;
    const unsigned total = N_TOK * DIM;     // 8388608
    for (unsigned o = blockIdx.x * blockDim.x + threadIdx.x; o < total; o += stride) {
        unsigned w = o & 31u;
        unsigned h = (o >> 5) & 31u;
        unsigned c = (o >> 10) & 255u;
        unsigned b = o >> 18;
        unsigned n = (b << 10) + (h << 5) + w;
        int idx = (int)idxf[n];
        float q = ew[(size_t)idx * DIM + c];
        float zv = z[o];
        zq[o] = q;
        float dx = q - zv;
        part = fmaf(dx, dx, part);
    }
    __shared__ float red[256];
    red[threadIdx.x] = part;
    __syncthreads();
    for (int s = 128; s > 0; s >>= 1) {
        if ((int)threadIdx.x < s) red[threadIdx.x] += red[threadIdx.x + s];
        __syncthreads();
    }
    if (threadIdx.x == 0) atomicAdd(sse, red[0]);
}

// ---------------------------------------------------------------------------
// finalize: loss scalar + perplexity via LDS histogram (single block).
// ---------------------------------------------------------------------------
__global__ __launch_bounds__(1024) void vq_finalize(const float* __restrict__ idxf,
                                                    const float* __restrict__ sse,
                                                    float* __restrict__ loss,
                                                    float* __restrict__ ppl)
{
    __shared__ int   hist[NE];
    __shared__ float red[NE];
    const int t = threadIdx.x;
    hist[t] = 0;
    __syncthreads();
    for (int i = t; i < N_TOK; i += 1024) {
        atomicAdd(&hist[(int)idxf[i]], 1);
    }
    __syncthreads();
    float p = (float)hist[t] * (1.0f / (float)N_TOK);
    red[t] = p * logf(p + 1e-10f);
    __syncthreads();
    for (int s = 512; s > 0; s >>= 1) {
        if (t < s) red[t] += red[t + s];
        __syncthreads();
    }
    if (t == 0) {
        ppl[0]  = expf(-red[0]);
        loss[0] = 0.25f * sse[0] / (float)(N_TOK * DIM);
    }
}

extern "C" void kernel_launch(void* const* d_in, const int* in_sizes, int n_in,
                              void* d_out, int out_size, void* d_ws, size_t ws_size,
                              hipStream_t stream)
{
    const float* z  = (const float*)d_in[0];   // (32,256,32,32)
    const float* ew = (const float*)d_in[1];   // (1024,256)
    float* out = (float*)d_out;
    float* wsf = (float*)d_ws;

    float* out_idx = out + OFF_IDX;
    float* out_oh  = out + OFF_OH;
    float* out_zq  = out + OFF_ZQ;
    float* out_ppl = out + OFF_PPL;

    vq_init<<<1, 1, 0, stream>>>(wsf);
    vq_argmin<<<512, 256, 0, stream>>>(z, ew, out_idx);
    vq_onehot<<<2048, 256, 0, stream>>>(out_idx, out_oh);
    vq_gather<<<2048, 256, 0, stream>>>(z, ew, out_idx, out_zq, wsf);
    vq_finalize<<<1, 1024, 0, stream>>>(out_idx, wsf, out, out_ppl);
}

// Round 2
// 365.215 us; speedup vs baseline: 1.4068x; 1.4068x over previous
//
#include <hip/hip_runtime.h>
#include <math.h>

// Problem constants
#define N_TOK 32768      // 32*32*32 tokens
#define NE    1024       // codebook size
#define DIM   256        // code dim

// d_out layout (fp32 elements):
//  [0] loss | [1..8388609) z_q_st | [8388609] ppl | [8388610..+33554432) one_hot
//  | [41943042..+32768) indices (float)
#define OFF_ZQ   1u
#define OFF_PPL  8388609u
#define OFF_OH   8388610u
#define OFF_IDX  41943042u

// scratch placed inside the one_hot output region (overwritten by vq_onehot later)
#define P_D_OFF  0u          // 32768*8 floats: partial best dist per (row, colblock)
#define P_I_OFF  262144u     // 32768*8 ints:   partial best idx
#define ZN_OFF   524288u     // 32768 floats: row norms
#define EN_OFF   557056u     // 1024 floats:  code norms

// GEMM tiling
#define BM 128
#define BN 128
#define BK 32
#define ESTR 144             // swizzled B-tile row stride (floats)

__global__ void vq_init(float* wsf) { wsf[0] = 0.0f; }

// ---------------------------------------------------------------------------
// Row/code squared norms — identical sequential-fmaf order as round 1.
// ---------------------------------------------------------------------------
__global__ __launch_bounds__(256) void vq_norms(const float* __restrict__ z,
                                                const float* __restrict__ ew,
                                                float* __restrict__ zn,
                                                float* __restrict__ en)
{
    int gid = blockIdx.x * 256 + threadIdx.x;
    if (gid < N_TOK) {
        int bimg = gid >> 10, hw = gid & 1023;
        const float* p = z + (size_t)bimg * (DIM * 1024) + hw;
        float s = 0.f;
#pragma unroll 8
        for (int d = 0; d < DIM; ++d) { float v = p[d * 1024]; s = fmaf(v, v, s); }
        zn[gid] = s;
    } else if (gid < N_TOK + NE) {
        int c = gid - N_TOK;
        const float* p = ew + (size_t)c * DIM;
        float s = 0.f;
#pragma unroll 8
        for (int d = 0; d < DIM; ++d) { float v = p[d]; s = fmaf(v, v, s); }
        en[c] = s;
    }
}

// ---------------------------------------------------------------------------
// Argmin GEMM: block = 128 rows x 128 codes, 8x8 register tile / thread.
// grid = 256 rowblocks x 8 colblocks. Partial (bestd, bestidx) per colblock.
// A-fragment LDS reads broadcast (4 distinct addrs/wave); B-fragment reads
// conflict-free via swz(c) = c + 4*(c>>5) pad swizzle (2-way max = free).
// Dot accumulation: sequential fmaf over d=0..255 -> bit-identical to round 1.
// ---------------------------------------------------------------------------
__global__ __launch_bounds__(256, 3) void vq_argmin(const float* __restrict__ z,
                                                    const float* __restrict__ ew,
                                                    const float* __restrict__ zn,
                                                    const float* __restrict__ en,
                                                    float* __restrict__ pd,
                                                    int*   __restrict__ pi)
{
    __shared__ __align__(16) float zs[BK][BM];    // 16 KB
    __shared__ __align__(16) float es[BK][ESTR];  // 18 KB

    const int t    = threadIdx.x;
    const int rb   = blockIdx.x & 255;
    const int cbi  = blockIdx.x >> 8;
    const int r0   = rb * BM;
    const int c0   = cbi * BN;
    const int bimg = r0 >> 10;
    const int hw0  = r0 & 1023;
    const float* zb = z + (size_t)bimg * (DIM * 1024) + hw0;

    const int tx = t & 15, ty = t >> 4;
    const int sb = tx * 8 + 4 * (tx >> 2);        // swizzled B base

    const int acq = t & 31, arr = t >> 5;         // A staging: col-quad, row
    const int bc  = t & 127, bh = t >> 7;         // B staging: code, k-half
    const int scw = bc + 4 * (bc >> 5);           // swizzled write col

    float acc[8][8];
#pragma unroll
    for (int i = 0; i < 8; ++i)
#pragma unroll
        for (int j = 0; j < 8; ++j) acc[i][j] = 0.f;

    for (int kc = 0; kc < DIM / BK; ++kc) {
        const int k0 = kc * BK;
        if (kc) __syncthreads();
        // stage A tile [BK][BM]: coalesced float4 reads, contiguous b128 writes
#pragma unroll
        for (int it = 0; it < 4; ++it) {
            int row = it * 8 + arr;
            float4 v = *reinterpret_cast<const float4*>(zb + (size_t)(k0 + row) * 1024 + acq * 4);
            *reinterpret_cast<float4*>(&zs[row][acq * 4]) = v;
        }
        // stage B tile [BK][swz(c)]: transpose from e_w[c][d]
        {
            const float* ebase = ew + (size_t)(c0 + bc) * DIM + k0 + bh * 16;
#pragma unroll
            for (int j = 0; j < 4; ++j) {
                float4 v = *reinterpret_cast<const float4*>(ebase + 4 * j);
                es[bh * 16 + 4 * j + 0][scw] = v.x;
                es[bh * 16 + 4 * j + 1][scw] = v.y;
                es[bh * 16 + 4 * j + 2][scw] = v.z;
                es[bh * 16 + 4 * j + 3][scw] = v.w;
            }
        }
        __syncthreads();

        const float* zp = &zs[0][ty * 8];
        const float* ep = &es[0][sb];
#pragma unroll 8
        for (int k = 0; k < BK; ++k) {
            float4 a0 = *reinterpret_cast<const float4*>(zp);
            float4 a1 = *reinterpret_cast<const float4*>(zp + 4);
            float4 b0 = *reinterpret_cast<const float4*>(ep);
            float4 b1 = *reinterpret_cast<const float4*>(ep + 4);
            zp += BM; ep += ESTR;
            float a[8] = {a0.x, a0.y, a0.z, a0.w, a1.x, a1.y, a1.z, a1.w};
            float b[8] = {b0.x, b0.y, b0.z, b0.w, b1.x, b1.y, b1.z, b1.w};
#pragma unroll
            for (int i = 0; i < 8; ++i)
#pragma unroll
                for (int j = 0; j < 8; ++j)
                    acc[i][j] = fmaf(a[i], b[j], acc[i][j]);
        }
    }

    // epilogue: dist = (zn + en) - 2*dot, per-row argmin (ascending code order)
    float znr[8], enj[8];
#pragma unroll
    for (int i = 0; i < 8; ++i) znr[i] = zn[r0 + ty * 8 + i];
#pragma unroll
    for (int j = 0; j < 8; ++j) enj[j] = en[c0 + tx * 8 + j];

    __syncthreads();
    float* rd = &zs[0][0];                              // [128][16] dists
    int*   ri = reinterpret_cast<int*>(&zs[0][0]) + 2048;  // [128][16] idxs

#pragma unroll
    for (int i = 0; i < 8; ++i) {
        float bd = 3.0e38f; int bi = 0;
#pragma unroll
        for (int j = 0; j < 8; ++j) {
            float dv = (znr[i] + enj[j]) - 2.0f * acc[i][j];
            if (dv < bd) { bd = dv; bi = c0 + tx * 8 + j; }
        }
        rd[(ty * 8 + i) * 16 + tx] = bd;
        ri[(ty * 8 + i) * 16 + tx] = bi;
    }
    __syncthreads();
    if (t < 128) {
        float bd = rd[t * 16]; int bi = ri[t * 16];
#pragma unroll
        for (int c = 1; c < 16; ++c) {
            float dc = rd[t * 16 + c]; int ic = ri[t * 16 + c];
            if (dc < bd || (dc == bd && ic < bi)) { bd = dc; bi = ic; }
        }
        pd[(size_t)(r0 + t) * 8 + cbi] = bd;
        pi[(size_t)(r0 + t) * 8 + cbi] = bi;
    }
}

// ---------------------------------------------------------------------------
// merge 8 column-block partials per row (ascending -> first-min tie-break)
// ---------------------------------------------------------------------------
__global__ __launch_bounds__(256) void vq_reduce(const float* __restrict__ pd,
                                                 const int* __restrict__ pi,
                                                 float* __restrict__ out_idx)
{
    int r = blockIdx.x * 256 + threadIdx.x;
    if (r >= N_TOK) return;
    float bd = pd[(size_t)r * 8]; int bi = pi[(size_t)r * 8];
#pragma unroll
    for (int c = 1; c < 8; ++c) {
        float dc = pd[(size_t)r * 8 + c]; int ic = pi[(size_t)r * 8 + c];
        if (dc < bd || (dc == bd && ic < bi)) { bd = dc; bi = ic; }
    }
    out_idx[r] = (float)bi;
}

// ---------------------------------------------------------------------------
// one_hot: 33.5M floats (8B-aligned region -> float2 stores)
// ---------------------------------------------------------------------------
__global__ __launch_bounds__(256) void vq_onehot(const float* __restrict__ idxf,
                                                 float* __restrict__ oh)
{
    const unsigned stride = gridDim.x * blockDim.x;
    const unsigned total2 = N_TOK * (NE / 2);
    for (unsigned o2 = blockIdx.x * blockDim.x + threadIdx.x; o2 < total2; o2 += stride) {
        unsigned n = o2 >> 7;
        int k = (int)((o2 & 127u) << 1);
        int idx = (int)idxf[n];
        float2 v;
        v.x = (k == idx) ? 1.0f : 0.0f;
        v.y = (k + 1 == idx) ? 1.0f : 0.0f;
        reinterpret_cast<float2*>(oh)[o2] = v;
    }
}

// ---------------------------------------------------------------------------
// z_q gather + SSE accumulation (4B-aligned region -> scalar stores)
// ---------------------------------------------------------------------------
__global__ __launch_bounds__(256) void vq_gather(const float* __restrict__ z,
                                                 const float* __restrict__ ew,
                                                 const float* __restrict__ idxf,
                                                 float* __restrict__ zq,
                                                 float* __restrict__ sse)
{
    float part = 0.0f;
    const unsigned stride = gridDim.x * blockDim.x;
    const unsigned total = N_TOK * DIM;
    for (unsigned o = blockIdx.x * blockDim.x + threadIdx.x; o < total; o += stride) {
        unsigned w = o & 31u;
        unsigned h = (o >> 5) & 31u;
        unsigned c = (o >> 10) & 255u;
        unsigned b = o >> 18;
        unsigned n = (b << 10) + (h << 5) + w;
        int idx = (int)idxf[n];
        float q = ew[(size_t)idx * DIM + c];
        float zv = z[o];
        zq[o] = q;
        float dx = q - zv;
        part = fmaf(dx, dx, part);
    }
    __shared__ float red[256];
    red[threadIdx.x] = part;
    __syncthreads();
    for (int s = 128; s > 0; s >>= 1) {
        if ((int)threadIdx.x < s) red[threadIdx.x] += red[threadIdx.x + s];
        __syncthreads();
    }
    if (threadIdx.x == 0) atomicAdd(sse, red[0]);
}

// ---------------------------------------------------------------------------
// finalize: loss + perplexity (single block, LDS histogram)
// ---------------------------------------------------------------------------
__global__ __launch_bounds__(1024) void vq_finalize(const float* __restrict__ idxf,
                                                    const float* __restrict__ sse,
                                                    float* __restrict__ loss,
                                                    float* __restrict__ ppl)
{
    __shared__ int   hist[NE];
    __shared__ float red[NE];
    const int t = threadIdx.x;
    hist[t] = 0;
    __syncthreads();
    for (int i = t; i < N_TOK; i += 1024) {
        atomicAdd(&hist[(int)idxf[i]], 1);
    }
    __syncthreads();
    float p = (float)hist[t] * (1.0f / (float)N_TOK);
    red[t] = p * logf(p + 1e-10f);
    __syncthreads();
    for (int s = 512; s > 0; s >>= 1) {
        if (t < s) red[t] += red[t + s];
        __syncthreads();
    }
    if (t == 0) {
        ppl[0]  = expf(-red[0]);
        loss[0] = 0.25f * sse[0] / (float)(N_TOK * DIM);
    }
}

extern "C" void kernel_launch(void* const* d_in, const int* in_sizes, int n_in,
                              void* d_out, int out_size, void* d_ws, size_t ws_size,
                              hipStream_t stream)
{
    const float* z  = (const float*)d_in[0];   // (32,256,32,32)
    const float* ew = (const float*)d_in[1];   // (1024,256)
    float* out = (float*)d_out;
    float* wsf = (float*)d_ws;

    float* out_idx = out + OFF_IDX;
    float* out_oh  = out + OFF_OH;
    float* out_zq  = out + OFF_ZQ;
    float* out_ppl = out + OFF_PPL;

    // scratch inside one_hot region (overwritten by vq_onehot afterwards)
    float* PD = out_oh + P_D_OFF;
    int*   PI = (int*)(out_oh + P_I_OFF);
    float* ZN = out_oh + ZN_OFF;
    float* EN = out_oh + EN_OFF;

    vq_init<<<1, 1, 0, stream>>>(wsf);
    vq_norms<<<132, 256, 0, stream>>>(z, ew, ZN, EN);
    vq_argmin<<<2048, 256, 0, stream>>>(z, ew, ZN, EN, PD, PI);
    vq_reduce<<<128, 256, 0, stream>>>(PD, PI, out_idx);
    vq_onehot<<<2048, 256, 0, stream>>>(out_idx, out_oh);
    vq_gather<<<2048, 256, 0, stream>>>(z, ew, out_idx, out_zq, wsf);
    vq_finalize<<<1, 1024, 0, stream>>>(out_idx, wsf, out, out_ppl);
}

// Round 5
// 327.908 us; speedup vs baseline: 1.5669x; 1.1138x over previous
//
#include <hip/hip_runtime.h>
#include <math.h>

// Problem constants
#define N_TOK 32768      // 32*32*32 tokens
#define NE    1024       // codebook size
#define DIM   256        // code dim
#define EPS   2.5e-4f    // candidate margin >> 2*delta (delta ~ 4e-5)

// d_out layout (fp32 elements):
//  [0] loss | [1..8388609) z_q_st | [8388609] ppl | [8388610..+33554432) one_hot
//  | [41943042..+32768) indices (float)
#define OFF_ZQ   1u
#define OFF_PPL  8388609u
#define OFF_OH   8388610u
#define OFF_IDX  41943042u

// Scratch inside the one_hot output region (overwritten by vq_onehot later).
// Byte offsets relative to sc = (char*)(out + OFF_OH). oh base byte addr = 8 mod 16,
// so offsets = 8 mod 16 are absolutely 16B-aligned.
#define ZS_BYTES 16777216u            // one z-split: 32768*256*2B
#define ES_BYTES 524288u              // one e-split: 1024*256*2B
#define ZS0_B    8u
#define ZS1_B    (ZS0_B + ZS_BYTES)          // 16777224
#define ES0_B    (ZS0_B + 2u*ZS_BYTES)       // 33554440
#define ES1_B    (ES0_B + ES_BYTES)          // 34078728
#define ZT32_B   (ES0_B + 2u*ES_BYTES)       // 34603016: fp32 token-major z, 32 MB
#define CM_B     (ZT32_B + 33554432u)        // 68157448: cand masks, 32768*16 u64 = 4 MB
#define ZN_B     (CM_B + 4194304u)           // 72351752
#define EN_B     (ZN_B + 131072u)            // 72482824  (end < 134217728 OK)

typedef __attribute__((ext_vector_type(8))) short short8;
typedef __attribute__((ext_vector_type(8))) unsigned short ushort8;
typedef __attribute__((ext_vector_type(4))) float f32x4;

__device__ __forceinline__ unsigned short bf_rne(float f) {
    unsigned u = __float_as_uint(f);
    return (unsigned short)((u + 0x7FFFu + ((u >> 16) & 1u)) >> 16);
}
__device__ __forceinline__ float bf_tof(unsigned short h) {
    return __uint_as_float(((unsigned)h) << 16);
}
__device__ __forceinline__ void gload16(const void* g, void* l) {
    __builtin_amdgcn_global_load_lds((const __attribute__((address_space(1))) void*)g,
                                     (__attribute__((address_space(3))) void*)l, 16, 0, 0);
}

__global__ void vq_init(float* wsf) { wsf[0] = 0.0f; }

// ---------------------------------------------------------------------------
// z prep: transpose z[b][c][hw] -> token-major bf16 2-splits + fp32 copy, and
// zn[token] with the SAME fmaf order as round 2 (bit-identical).
// ---------------------------------------------------------------------------
__global__ __launch_bounds__(256) void vq_zprep(const float* __restrict__ z,
                                                char* __restrict__ sc,
                                                float* __restrict__ zn)
{
    __shared__ float zf[64 * 257];   // [hw][c] padded stride 257
    const int t = threadIdx.x;
    const int img = blockIdx.x >> 4;
    const int hw0 = (blockIdx.x & 15) << 6;
    const float* zb = z + (size_t)img * (DIM * 1024) + hw0;

#pragma unroll 4
    for (int it = 0; it < 64; ++it) {
        int idx = it * 256 + t;
        int c = idx >> 6, hw = idx & 63;
        zf[hw * 257 + c] = zb[(size_t)c * 1024 + hw];
    }
    __syncthreads();

    if (t < 64) {
        float s = 0.0f;
#pragma unroll 8
        for (int c = 0; c < DIM; ++c) { float v = zf[t * 257 + c]; s = fmaf(v, v, s); }
        zn[img * 1024 + hw0 + t] = s;
    }
    __syncthreads();

#pragma unroll
    for (int it = 0; it < 8; ++it) {
        int f = it * 256 + t;
        int tl = f >> 5, cg = f & 31;
        ushort8 s1, s2;
        float vv[8];
#pragma unroll
        for (int j = 0; j < 8; ++j) {
            float v = zf[tl * 257 + cg * 8 + j];
            vv[j] = v;
            unsigned short b1 = bf_rne(v); float r1 = v - bf_tof(b1);
            unsigned short b2 = bf_rne(r1);
            s1[j] = b1; s2[j] = b2;
        }
        int tok = img * 1024 + hw0 + tl;
        size_t eo = ((size_t)tok * 256 + cg * 8) * 2;
        *reinterpret_cast<ushort8*>(sc + ZS0_B + eo) = s1;
        *reinterpret_cast<ushort8*>(sc + ZS1_B + eo) = s2;
        size_t eo2 = ((size_t)tok * 256 + cg * 8) * 4;
        float4 f0 = make_float4(vv[0], vv[1], vv[2], vv[3]);
        float4 f1 = make_float4(vv[4], vv[5], vv[6], vv[7]);
        *reinterpret_cast<float4*>(sc + ZT32_B + eo2) = f0;
        *reinterpret_cast<float4*>(sc + ZT32_B + eo2 + 16) = f1;
    }
}

// ---------------------------------------------------------------------------
// e prep: bf16 2-way split of e_w + en (same fmaf order as round 2).
// ---------------------------------------------------------------------------
__global__ __launch_bounds__(256) void vq_eprep(const float* __restrict__ ew,
                                                char* __restrict__ sc,
                                                float* __restrict__ en)
{
    const int code = blockIdx.x * 256 + threadIdx.x;
    const float* p = ew + (size_t)code * DIM;
    float s = 0.0f;
    for (int dg = 0; dg < 32; ++dg) {
        ushort8 s1, s2;
#pragma unroll
        for (int j = 0; j < 8; ++j) {
            float v = p[dg * 8 + j];
            s = fmaf(v, v, s);
            unsigned short b1 = bf_rne(v); float r1 = v - bf_tof(b1);
            unsigned short b2 = bf_rne(r1);
            s1[j] = b1; s2[j] = b2;
        }
        size_t eo = ((size_t)code * 256 + dg * 8) * 2;
        *reinterpret_cast<ushort8*>(sc + ES0_B + eo) = s1;
        *reinterpret_cast<ushort8*>(sc + ES1_B + eo) = s2;
    }
    en[code] = s;
}

// ---------------------------------------------------------------------------
// MFMA prepass: 128 tokens x 128 codes per block, 4 waves (2x2), BK=32,
// 2x2 bf16 splits = 4 products (dot error ~5e-6, quantization-dominated).
// Output: per-token 128-bit candidate mask (d <= blockmin + EPS) per block.
// Grid: cbi = blk&7 (fastest) so consecutive blocks reuse z rows in L2.
// ---------------------------------------------------------------------------
__global__ __launch_bounds__(256) void vq_argmin_mfma(const char* __restrict__ sc,
                                                      const float* __restrict__ zn,
                                                      const float* __restrict__ en,
                                                      unsigned long long* __restrict__ cmu)
{
    __shared__ short lds[2][16384];   // 2 x 32KB: za0,za1,eb0,eb1 each [128][32]

    const int t = threadIdx.x;
    const int lane = t & 63, w = t >> 6;
    const int wr = w >> 1, wc = w & 1;
    const int rb = blockIdx.x >> 3, cbi = blockIdx.x & 7;
    const int r0 = rb * 128, c0 = cbi * 128;

    unsigned srcoff[8];
#pragma unroll
    for (int i = 0; i < 8; ++i) {
        int flat = (w * 8 + i) * 64 + lane;    // 16B-slot id 0..2047
        int arr = flat >> 9;                    // 0,1 = z-splits; 2,3 = e-splits
        int rr  = (flat & 511) >> 2;            // row 0..127
        int sl  = flat & 3;                     // physical k-slot
        int slx = sl ^ ((rr >> 1) & 3);         // source k-slot (pre-swizzle)
        unsigned off;
        if (arr < 2) off = ZS0_B + (unsigned)arr * ZS_BYTES
                         + (unsigned)(((r0 + rr) * 256 + slx * 8) * 2);
        else         off = ES0_B + (unsigned)(arr - 2) * ES_BYTES
                         + (unsigned)(((c0 + rr) * 256 + slx * 8) * 2);
        srcoff[i] = off;
    }

    f32x4 acc[4][4];
#pragma unroll
    for (int i = 0; i < 4; ++i)
#pragma unroll
        for (int j = 0; j < 4; ++j) acc[i][j] = (f32x4)0.0f;

#pragma unroll
    for (int i = 0; i < 8; ++i)
        gload16(sc + srcoff[i], &lds[0][(w * 8 + i) * 512]);
    __syncthreads();

    int cur = 0;
    for (int kc = 0; kc < 8; ++kc) {
        if (kc < 7) {
            const unsigned kadd = (unsigned)(kc + 1) * 64u;   // +32 bf16 per chunk
#pragma unroll
            for (int i = 0; i < 8; ++i)
                gload16(sc + srcoff[i] + kadd, &lds[cur ^ 1][(w * 8 + i) * 512]);
        }
        const short* L = &lds[cur][0];
        const short* za0 = L;
        const short* za1 = L + 4096;
        const short* eb0 = L + 8192;
        const short* eb1 = L + 12288;

        short8 bfr0[4], bfr1[4];
#pragma unroll
        for (int fn = 0; fn < 4; ++fn) {
            int row = wc * 64 + fn * 16 + (lane & 15);
            int slot = (lane >> 4) ^ ((row >> 1) & 3);
            bfr0[fn] = *reinterpret_cast<const short8*>(eb0 + row * 32 + slot * 8);
            bfr1[fn] = *reinterpret_cast<const short8*>(eb1 + row * 32 + slot * 8);
        }
#pragma unroll
        for (int fm = 0; fm < 4; ++fm) {
            int row = wr * 64 + fm * 16 + (lane & 15);
            int slot = (lane >> 4) ^ ((row >> 1) & 3);
            short8 a0 = *reinterpret_cast<const short8*>(za0 + row * 32 + slot * 8);
            short8 a1 = *reinterpret_cast<const short8*>(za1 + row * 32 + slot * 8);
#pragma unroll
            for (int fn = 0; fn < 4; ++fn) {
                acc[fm][fn] = __builtin_amdgcn_mfma_f32_16x16x32_bf16(a0, bfr0[fn], acc[fm][fn], 0, 0, 0);
                acc[fm][fn] = __builtin_amdgcn_mfma_f32_16x16x32_bf16(a0, bfr1[fn], acc[fm][fn], 0, 0, 0);
                acc[fm][fn] = __builtin_amdgcn_mfma_f32_16x16x32_bf16(a1, bfr0[fn], acc[fm][fn], 0, 0, 0);
                acc[fm][fn] = __builtin_amdgcn_mfma_f32_16x16x32_bf16(a1, bfr1[fn], acc[fm][fn], 0, 0, 0);
            }
        }
        __syncthreads();
        cur ^= 1;
    }

    // ---- epilogue phase 1: per-row block-min (cross-wave merged, race-free)
    float env[4];
#pragma unroll
    for (int fn = 0; fn < 4; ++fn)
        env[fn] = en[c0 + wc * 64 + fn * 16 + (lane & 15)];

    float* sdm = reinterpret_cast<float*>(&lds[0][0]);   // [2][128]

#pragma unroll
    for (int fm = 0; fm < 4; ++fm) {
#pragma unroll
        for (int reg = 0; reg < 4; ++reg) {
            int lrow = wr * 64 + fm * 16 + ((lane >> 4) << 2) + reg;
            float znv = zn[r0 + lrow];
            float bd = 3.0e38f;
#pragma unroll
            for (int fn = 0; fn < 4; ++fn) {
                float dv = (znv + env[fn]) - 2.0f * acc[fm][fn][reg];
                bd = fminf(bd, dv);
            }
#pragma unroll
            for (int m = 1; m <= 8; m <<= 1)
                bd = fminf(bd, __shfl_xor(bd, m));
            if ((lane & 15) == 0) sdm[wc * 128 + lrow] = bd;
        }
    }
    __syncthreads();
    if (t < 128) sdm[t] = fminf(sdm[t], sdm[128 + t]) + EPS;   // threshold per row
    __syncthreads();

    // ---- epilogue phase 2: ballot candidates, assemble 64-bit half-masks
#pragma unroll
    for (int fm = 0; fm < 4; ++fm) {
        unsigned long long bl[4][4];
#pragma unroll
        for (int fn = 0; fn < 4; ++fn) {
#pragma unroll
            for (int reg = 0; reg < 4; ++reg) {
                int lrow = wr * 64 + fm * 16 + ((lane >> 4) << 2) + reg;
                float thr = sdm[lrow];
                float dv = (zn[r0 + lrow] + env[fn]) - 2.0f * acc[fm][fn][reg];
                bl[fn][reg] = __ballot(dv <= thr);
            }
        }
        const int q = lane >> 4;
#pragma unroll
        for (int reg = 0; reg < 4; ++reg) {
            unsigned long long h =
                  ((bl[0][reg] >> (q * 16)) & 0xFFFFull)
                | (((bl[1][reg] >> (q * 16)) & 0xFFFFull) << 16)
                | (((bl[2][reg] >> (q * 16)) & 0xFFFFull) << 32)
                | (((bl[3][reg] >> (q * 16)) & 0xFFFFull) << 48);
            if ((lane & 15) == reg) {
                int row = wr * 64 + fm * 16 + q * 4 + reg;
                cmu[(size_t)(r0 + row) * 16 + cbi * 2 + wc] = h;
            }
        }
    }
}

// ---------------------------------------------------------------------------
// Exact rescore: one wave per token. Compact the 1024-bit candidate mask,
// recompute each candidate's distance with the round-2-exact fp32 formula
// (ascending scalar fmaf), lexicographic (d, idx) min == reference argmin.
// ---------------------------------------------------------------------------
__global__ __launch_bounds__(256) void vq_rescore(const char* __restrict__ sc,
                                                  const float* __restrict__ ew,
                                                  const float* __restrict__ zn,
                                                  const float* __restrict__ en,
                                                  float* __restrict__ out_idx)
{
    __shared__ float zrow[4][256];
    __shared__ int   list[4][1024];
    const int t = threadIdx.x, lane = t & 63, ws = t >> 6;
    const int tok = blockIdx.x * 4 + ws;

    const unsigned long long* cmu = reinterpret_cast<const unsigned long long*>(sc + CM_B);
    const float* zt32 = reinterpret_cast<const float*>(sc + ZT32_B);

    *reinterpret_cast<float4*>(&zrow[ws][lane * 4]) =
        *reinterpret_cast<const float4*>(zt32 + (size_t)tok * 256 + lane * 4);

    int total = 0;
    for (int wd = 0; wd < 16; ++wd) {
        unsigned long long v = cmu[(size_t)tok * 16 + wd];
        int cnt = __popcll(v);
        if (cnt) {
            if ((v >> lane) & 1ull) {
                int rank = __popcll(v & ((1ull << lane) - 1ull));
                list[ws][total + rank] = (wd >> 1) * 128 + (wd & 1) * 64 + lane;
            }
            total += cnt;
        }
    }

    const float znv = zn[tok];
    float bd = 3.0e38f; int bi = 0x7FFFFFFF;
    for (int b0 = 0; b0 < total; b0 += 64) {
        int myi = b0 + lane;
        bool a = myi < total;
        int code = a ? list[ws][myi] : 0;
        float s = 0.0f;
        if (a) {
            const float* ep = ew + (size_t)code * DIM;
            const float* zr = &zrow[ws][0];
#pragma unroll 8
            for (int d = 0; d < DIM; ++d) s = fmaf(zr[d], ep[d], s);
        }
        float dv = a ? (znv + en[code]) - 2.0f * s : 3.0e38f;
        int ii = a ? code : 0x7FFFFFFF;
        if (dv < bd || (dv == bd && ii < bi)) { bd = dv; bi = ii; }
    }
#pragma unroll
    for (int m = 1; m <= 32; m <<= 1) {
        float od = __shfl_xor(bd, m);
        int   oi = __shfl_xor(bi, m);
        if (od < bd || (od == bd && oi < bi)) { bd = od; bi = oi; }
    }
    if (lane == 0) out_idx[tok] = (float)bi;
}

// ---------------------------------------------------------------------------
// one_hot: 33.5M floats (8B-aligned region -> float2 stores)
// ---------------------------------------------------------------------------
__global__ __launch_bounds__(256) void vq_onehot(const float* __restrict__ idxf,
                                                 float* __restrict__ oh)
{
    const unsigned stride = gridDim.x * blockDim.x;
    const unsigned total2 = N_TOK * (NE / 2);
    for (unsigned o2 = blockIdx.x * blockDim.x + threadIdx.x; o2 < total2; o2 += stride) {
        unsigned n = o2 >> 7;
        int k = (int)((o2 & 127u) << 1);
        int idx = (int)idxf[n];
        float2 v;
        v.x = (k == idx) ? 1.0f : 0.0f;
        v.y = (k + 1 == idx) ? 1.0f : 0.0f;
        reinterpret_cast<float2*>(oh)[o2] = v;
    }
}

// ---------------------------------------------------------------------------
// z_q gather + SSE accumulation (4B-aligned region -> scalar stores)
// ---------------------------------------------------------------------------
__global__ __launch_bounds__(256) void vq_gather(const float* __restrict__ z,
                                                 const float* __restrict__ ew,
                                                 const float* __restrict__ idxf,
                                                 float* __restrict__ zq,
                                                 float* __restrict__ sse)
{
    float part = 0.0f;
    const unsigned stride = gridDim.x * blockDim.x;
    const unsigned total = N_TOK * DIM;
    for (unsigned o = blockIdx.x * blockDim.x + threadIdx.x; o < total; o += stride) {
        unsigned w = o & 31u;
        unsigned h = (o >> 5) & 31u;
        unsigned c = (o >> 10) & 255u;
        unsigned b = o >> 18;
        unsigned n = (b << 10) + (h << 5) + w;
        int idx = (int)idxf[n];
        float q = ew[(size_t)idx * DIM + c];
        float zv = z[o];
        zq[o] = q;
        float dx = q - zv;
        part = fmaf(dx, dx, part);
    }
    __shared__ float red[256];
    red[threadIdx.x] = part;
    __syncthreads();
    for (int s = 128; s > 0; s >>= 1) {
        if ((int)threadIdx.x < s) red[threadIdx.x] += red[threadIdx.x + s];
        __syncthreads();
    }
    if (threadIdx.x == 0) atomicAdd(sse, red[0]);
}

// ---------------------------------------------------------------------------
// finalize: loss + perplexity (single block, LDS histogram)
// ---------------------------------------------------------------------------
__global__ __launch_bounds__(1024) void vq_finalize(const float* __restrict__ idxf,
                                                    const float* __restrict__ sse,
                                                    float* __restrict__ loss,
                                                    float* __restrict__ ppl)
{
    __shared__ int   hist[NE];
    __shared__ float red[NE];
    const int t = threadIdx.x;
    hist[t] = 0;
    __syncthreads();
    for (int i = t; i < N_TOK; i += 1024) {
        atomicAdd(&hist[(int)idxf[i]], 1);
    }
    __syncthreads();
    float p = (float)hist[t] * (1.0f / (float)N_TOK);
    red[t] = p * logf(p + 1e-10f);
    __syncthreads();
    for (int s = 512; s > 0; s >>= 1) {
        if (t < s) red[t] += red[t + s];
        __syncthreads();
    }
    if (t == 0) {
        ppl[0]  = expf(-red[0]);
        loss[0] = 0.25f * sse[0] / (float)(N_TOK * DIM);
    }
}

extern "C" void kernel_launch(void* const* d_in, const int* in_sizes, int n_in,
                              void* d_out, int out_size, void* d_ws, size_t ws_size,
                              hipStream_t stream)
{
    const float* z  = (const float*)d_in[0];   // (32,256,32,32)
    const float* ew = (const float*)d_in[1];   // (1024,256)
    float* out = (float*)d_out;
    float* wsf = (float*)d_ws;

    float* out_idx = out + OFF_IDX;
    float* out_oh  = out + OFF_OH;
    float* out_zq  = out + OFF_ZQ;
    float* out_ppl = out + OFF_PPL;

    char*  sc = (char*)out_oh;                 // scratch inside one_hot region
    float* ZN = (float*)(sc + ZN_B);
    float* EN = (float*)(sc + EN_B);
    unsigned long long* CM = (unsigned long long*)(sc + CM_B);

    vq_init<<<1, 1, 0, stream>>>(wsf);
    vq_zprep<<<512, 256, 0, stream>>>(z, sc, ZN);
    vq_eprep<<<4, 256, 0, stream>>>(ew, sc, EN);
    vq_argmin_mfma<<<2048, 256, 0, stream>>>(sc, ZN, EN, CM);
    vq_rescore<<<8192, 256, 0, stream>>>(sc, ew, ZN, EN, out_idx);
    vq_onehot<<<2048, 256, 0, stream>>>(out_idx, out_oh);
    vq_gather<<<2048, 256, 0, stream>>>(z, ew, out_idx, out_zq, wsf);
    vq_finalize<<<1, 1024, 0, stream>>>(out_idx, wsf, out, out_ppl);
}

// Round 6
// 267.422 us; speedup vs baseline: 1.9213x; 1.2262x over previous
//
#include <hip/hip_runtime.h>
#include <math.h>

// Problem constants
#define N_TOK 32768      // 32*32*32 tokens
#define NE    1024       // codebook size
#define DIM   256        // code dim
#define EPS   2.5e-4f    // candidate margin >> 2*delta (delta ~ 4e-5)

// d_out layout (fp32 elements):
//  [0] loss | [1..8388609) z_q_st | [8388609] ppl | [8388610..+33554432) one_hot
//  | [41943042..+32768) indices (float)
#define OFF_ZQ   1u
#define OFF_PPL  8388609u
#define OFF_OH   8388610u
#define OFF_IDX  41943042u

// Scratch inside the one_hot output region (overwritten by vq_onehot later).
// Byte offsets relative to sc = (char*)(out + OFF_OH). oh base byte addr = 8 mod 16,
// so offsets = 8 mod 16 are absolutely 16B-aligned.
#define ZS_BYTES 16777216u            // one z-split: 32768*256*2B
#define ES_BYTES 524288u              // one e-split: 1024*256*2B
#define ZS0_B    8u
#define ZS1_B    (ZS0_B + ZS_BYTES)          // 16777224
#define ES0_B    (ZS0_B + 2u*ZS_BYTES)       // 33554440
#define ES1_B    (ES0_B + ES_BYTES)          // 34078728
#define ZT32_B   (ES0_B + 2u*ES_BYTES)       // 34603016: fp32 token-major z, 32 MB
#define CM_B     (ZT32_B + 33554432u)        // 68157448: cand masks, 32768*16 u64 = 4 MB
#define ZN_B     (CM_B + 4194304u)           // 72351752
#define EN_B     (ZN_B + 131072u)            // 72482824  (end < 134217728 OK)

typedef __attribute__((ext_vector_type(8))) short short8;
typedef __attribute__((ext_vector_type(8))) unsigned short ushort8;
typedef __attribute__((ext_vector_type(4))) float f32x4;

__device__ __forceinline__ unsigned short bf_rne(float f) {
    unsigned u = __float_as_uint(f);
    return (unsigned short)((u + 0x7FFFu + ((u >> 16) & 1u)) >> 16);
}
__device__ __forceinline__ float bf_tof(unsigned short h) {
    return __uint_as_float(((unsigned)h) << 16);
}
__device__ __forceinline__ void gload16(const void* g, void* l) {
    __builtin_amdgcn_global_load_lds((const __attribute__((address_space(1))) void*)g,
                                     (__attribute__((address_space(3))) void*)l, 16, 0, 0);
}

__global__ void vq_init(float* wsf) { wsf[0] = 0.0f; }

// ---------------------------------------------------------------------------
// z prep: transpose z[b][c][hw] -> token-major bf16 2-splits + fp32 copy, and
// zn[token] with the SAME fmaf order as round 2 (bit-identical).
// ---------------------------------------------------------------------------
__global__ __launch_bounds__(256) void vq_zprep(const float* __restrict__ z,
                                                char* __restrict__ sc,
                                                float* __restrict__ zn)
{
    __shared__ float zf[64 * 257];   // [hw][c] padded stride 257
    const int t = threadIdx.x;
    const int img = blockIdx.x >> 4;
    const int hw0 = (blockIdx.x & 15) << 6;
    const float* zb = z + (size_t)img * (DIM * 1024) + hw0;

#pragma unroll 4
    for (int it = 0; it < 64; ++it) {
        int idx = it * 256 + t;
        int c = idx >> 6, hw = idx & 63;
        zf[hw * 257 + c] = zb[(size_t)c * 1024 + hw];
    }
    __syncthreads();

    if (t < 64) {
        float s = 0.0f;
#pragma unroll 8
        for (int c = 0; c < DIM; ++c) { float v = zf[t * 257 + c]; s = fmaf(v, v, s); }
        zn[img * 1024 + hw0 + t] = s;
    }
    __syncthreads();

#pragma unroll
    for (int it = 0; it < 8; ++it) {
        int f = it * 256 + t;
        int tl = f >> 5, cg = f & 31;
        ushort8 s1, s2;
        float vv[8];
#pragma unroll
        for (int j = 0; j < 8; ++j) {
            float v = zf[tl * 257 + cg * 8 + j];
            vv[j] = v;
            unsigned short b1 = bf_rne(v); float r1 = v - bf_tof(b1);
            unsigned short b2 = bf_rne(r1);
            s1[j] = b1; s2[j] = b2;
        }
        int tok = img * 1024 + hw0 + tl;
        size_t eo = ((size_t)tok * 256 + cg * 8) * 2;
        *reinterpret_cast<ushort8*>(sc + ZS0_B + eo) = s1;
        *reinterpret_cast<ushort8*>(sc + ZS1_B + eo) = s2;
        size_t eo2 = ((size_t)tok * 256 + cg * 8) * 4;
        float4 f0 = make_float4(vv[0], vv[1], vv[2], vv[3]);
        float4 f1 = make_float4(vv[4], vv[5], vv[6], vv[7]);
        *reinterpret_cast<float4*>(sc + ZT32_B + eo2) = f0;
        *reinterpret_cast<float4*>(sc + ZT32_B + eo2 + 16) = f1;
    }
}

// ---------------------------------------------------------------------------
// e prep: bf16 2-way split of e_w + en (same fmaf order as round 2).
// ---------------------------------------------------------------------------
__global__ __launch_bounds__(256) void vq_eprep(const float* __restrict__ ew,
                                                char* __restrict__ sc,
                                                float* __restrict__ en)
{
    const int code = blockIdx.x * 256 + threadIdx.x;
    const float* p = ew + (size_t)code * DIM;
    float s = 0.0f;
    for (int dg = 0; dg < 32; ++dg) {
        ushort8 s1, s2;
#pragma unroll
        for (int j = 0; j < 8; ++j) {
            float v = p[dg * 8 + j];
            s = fmaf(v, v, s);
            unsigned short b1 = bf_rne(v); float r1 = v - bf_tof(b1);
            unsigned short b2 = bf_rne(r1);
            s1[j] = b1; s2[j] = b2;
        }
        size_t eo = ((size_t)code * 256 + dg * 8) * 2;
        *reinterpret_cast<ushort8*>(sc + ES0_B + eo) = s1;
        *reinterpret_cast<ushort8*>(sc + ES1_B + eo) = s2;
    }
    en[code] = s;
}

// ---------------------------------------------------------------------------
// MFMA prepass: 128 tokens x 128 codes per block, 4 waves (2x2), BK=32,
// 2x2 bf16 splits = 4 products (dot error ~5e-6, quantization-dominated).
// Output: per-token 128-bit candidate mask (d <= blockmin + EPS) per block.
// ---------------------------------------------------------------------------
__global__ __launch_bounds__(256) void vq_argmin_mfma(const char* __restrict__ sc,
                                                      const float* __restrict__ zn,
                                                      const float* __restrict__ en,
                                                      unsigned long long* __restrict__ cmu)
{
    __shared__ short lds[2][16384];   // 2 x 32KB: za0,za1,eb0,eb1 each [128][32]

    const int t = threadIdx.x;
    const int lane = t & 63, w = t >> 6;
    const int wr = w >> 1, wc = w & 1;
    const int rb = blockIdx.x >> 3, cbi = blockIdx.x & 7;
    const int r0 = rb * 128, c0 = cbi * 128;

    unsigned srcoff[8];
#pragma unroll
    for (int i = 0; i < 8; ++i) {
        int flat = (w * 8 + i) * 64 + lane;    // 16B-slot id 0..2047
        int arr = flat >> 9;                    // 0,1 = z-splits; 2,3 = e-splits
        int rr  = (flat & 511) >> 2;            // row 0..127
        int sl  = flat & 3;                     // physical k-slot
        int slx = sl ^ ((rr >> 1) & 3);         // source k-slot (pre-swizzle)
        unsigned off;
        if (arr < 2) off = ZS0_B + (unsigned)arr * ZS_BYTES
                         + (unsigned)(((r0 + rr) * 256 + slx * 8) * 2);
        else         off = ES0_B + (unsigned)(arr - 2) * ES_BYTES
                         + (unsigned)(((c0 + rr) * 256 + slx * 8) * 2);
        srcoff[i] = off;
    }

    f32x4 acc[4][4];
#pragma unroll
    for (int i = 0; i < 4; ++i)
#pragma unroll
        for (int j = 0; j < 4; ++j) acc[i][j] = (f32x4)0.0f;

#pragma unroll
    for (int i = 0; i < 8; ++i)
        gload16(sc + srcoff[i], &lds[0][(w * 8 + i) * 512]);
    __syncthreads();

    int cur = 0;
    for (int kc = 0; kc < 8; ++kc) {
        if (kc < 7) {
            const unsigned kadd = (unsigned)(kc + 1) * 64u;   // +32 bf16 per chunk
#pragma unroll
            for (int i = 0; i < 8; ++i)
                gload16(sc + srcoff[i] + kadd, &lds[cur ^ 1][(w * 8 + i) * 512]);
        }
        const short* L = &lds[cur][0];
        const short* za0 = L;
        const short* za1 = L + 4096;
        const short* eb0 = L + 8192;
        const short* eb1 = L + 12288;

        short8 bfr0[4], bfr1[4];
#pragma unroll
        for (int fn = 0; fn < 4; ++fn) {
            int row = wc * 64 + fn * 16 + (lane & 15);
            int slot = (lane >> 4) ^ ((row >> 1) & 3);
            bfr0[fn] = *reinterpret_cast<const short8*>(eb0 + row * 32 + slot * 8);
            bfr1[fn] = *reinterpret_cast<const short8*>(eb1 + row * 32 + slot * 8);
        }
#pragma unroll
        for (int fm = 0; fm < 4; ++fm) {
            int row = wr * 64 + fm * 16 + (lane & 15);
            int slot = (lane >> 4) ^ ((row >> 1) & 3);
            short8 a0 = *reinterpret_cast<const short8*>(za0 + row * 32 + slot * 8);
            short8 a1 = *reinterpret_cast<const short8*>(za1 + row * 32 + slot * 8);
#pragma unroll
            for (int fn = 0; fn < 4; ++fn) {
                acc[fm][fn] = __builtin_amdgcn_mfma_f32_16x16x32_bf16(a0, bfr0[fn], acc[fm][fn], 0, 0, 0);
                acc[fm][fn] = __builtin_amdgcn_mfma_f32_16x16x32_bf16(a0, bfr1[fn], acc[fm][fn], 0, 0, 0);
                acc[fm][fn] = __builtin_amdgcn_mfma_f32_16x16x32_bf16(a1, bfr0[fn], acc[fm][fn], 0, 0, 0);
                acc[fm][fn] = __builtin_amdgcn_mfma_f32_16x16x32_bf16(a1, bfr1[fn], acc[fm][fn], 0, 0, 0);
            }
        }
        __syncthreads();
        cur ^= 1;
    }

    // ---- epilogue phase 1: per-row block-min (cross-wave merged, race-free)
    float env[4];
#pragma unroll
    for (int fn = 0; fn < 4; ++fn)
        env[fn] = en[c0 + wc * 64 + fn * 16 + (lane & 15)];

    float* sdm = reinterpret_cast<float*>(&lds[0][0]);   // [2][128]

#pragma unroll
    for (int fm = 0; fm < 4; ++fm) {
#pragma unroll
        for (int reg = 0; reg < 4; ++reg) {
            int lrow = wr * 64 + fm * 16 + ((lane >> 4) << 2) + reg;
            float znv = zn[r0 + lrow];
            float bd = 3.0e38f;
#pragma unroll
            for (int fn = 0; fn < 4; ++fn) {
                float dv = (znv + env[fn]) - 2.0f * acc[fm][fn][reg];
                bd = fminf(bd, dv);
            }
#pragma unroll
            for (int m = 1; m <= 8; m <<= 1)
                bd = fminf(bd, __shfl_xor(bd, m));
            if ((lane & 15) == 0) sdm[wc * 128 + lrow] = bd;
        }
    }
    __syncthreads();
    if (t < 128) sdm[t] = fminf(sdm[t], sdm[128 + t]) + EPS;   // threshold per row
    __syncthreads();

    // ---- epilogue phase 2: ballot candidates, assemble 64-bit half-masks
#pragma unroll
    for (int fm = 0; fm < 4; ++fm) {
        unsigned long long bl[4][4];
#pragma unroll
        for (int fn = 0; fn < 4; ++fn) {
#pragma unroll
            for (int reg = 0; reg < 4; ++reg) {
                int lrow = wr * 64 + fm * 16 + ((lane >> 4) << 2) + reg;
                float thr = sdm[lrow];
                float dv = (zn[r0 + lrow] + env[fn]) - 2.0f * acc[fm][fn][reg];
                bl[fn][reg] = __ballot(dv <= thr);
            }
        }
        const int q = lane >> 4;
#pragma unroll
        for (int reg = 0; reg < 4; ++reg) {
            unsigned long long h =
                  ((bl[0][reg] >> (q * 16)) & 0xFFFFull)
                | (((bl[1][reg] >> (q * 16)) & 0xFFFFull) << 16)
                | (((bl[2][reg] >> (q * 16)) & 0xFFFFull) << 32)
                | (((bl[3][reg] >> (q * 16)) & 0xFFFFull) << 48);
            if ((lane & 15) == reg) {
                int row = wr * 64 + fm * 16 + q * 4 + reg;
                cmu[(size_t)(r0 + row) * 16 + cbi * 2 + wc] = h;
            }
        }
    }
}

// ---------------------------------------------------------------------------
// Exact rescore (restructured): one block = 16 tokens. Each of the 256 threads
// owns one (token, mask-word); popcount + block prefix-scan builds a compact
// (tok,code) worklist; every thread rescores one pair with the round-2-exact
// ascending-d fmaf chain (float4 loads, order preserved). Per-token lexico-
// graphic (d, idx) min via packed u64 LDS atomicMin (d>0 here, so float-bit
// order == numeric order; low code wins ties == first-min).
// ---------------------------------------------------------------------------
#define RS_TOK 16
#define RS_CAP 4096

__global__ __launch_bounds__(256) void vq_rescore(const char* __restrict__ sc,
                                                  const float* __restrict__ ew,
                                                  const float* __restrict__ zn,
                                                  const float* __restrict__ en,
                                                  float* __restrict__ out_idx)
{
    __shared__ float zrow[RS_TOK * 260];            // 16.6 KB, float4-aligned rows
    __shared__ int   wl[RS_CAP];                    // 16 KB worklist: (tok<<10)|code
    __shared__ int   cnt[256];                      // scan buffer
    __shared__ unsigned long long best[RS_TOK];

    const int t = threadIdx.x;
    const int tok0 = blockIdx.x * RS_TOK;

    const unsigned long long* cmu = reinterpret_cast<const unsigned long long*>(sc + CM_B);
    const float* zt32 = reinterpret_cast<const float*>(sc + ZT32_B);

    // stage 16 z-rows (fp32), float4
#pragma unroll
    for (int i = 0; i < 4; ++i) {
        int f = i * 256 + t;                        // 1024 float4 slots
        int tk = f >> 6, d4 = f & 63;
        *reinterpret_cast<float4*>(&zrow[tk * 260 + d4 * 4]) =
            *reinterpret_cast<const float4*>(zt32 + (size_t)(tok0 + tk) * 256 + d4 * 4);
    }
    if (t < RS_TOK) best[t] = ~0ull;

    // one mask word per thread: tok = t>>4, wd = t&15
    unsigned long long v = cmu[(size_t)(tok0 + (t >> 4)) * 16 + (t & 15)];
    int myc = __popcll(v);
    cnt[t] = myc;
    __syncthreads();
    // inclusive Hillis-Steele scan over 256
    for (int st = 1; st < 256; st <<= 1) {
        int x = cnt[t];
        int y = (t >= st) ? cnt[t - st] : 0;
        __syncthreads();
        cnt[t] = x + y;
        __syncthreads();
    }
    int base = cnt[t] - myc;                        // exclusive prefix
    int total = cnt[255];
    // expand set bits into worklist
    {
        const int wd = t & 15, tk = t >> 4;
        unsigned long long vv = v;
        while (vv) {
            int b = __ffsll((long long)vv) - 1;
            vv &= vv - 1;
            int code = (wd >> 1) * 128 + (wd & 1) * 64 + b;
            if (base < RS_CAP) wl[base] = (tk << 10) | code;
            ++base;
        }
    }
    __syncthreads();
    if (total > RS_CAP) total = RS_CAP;

    for (int p = t; p < total; p += 256) {
        int e = wl[p];
        int tk = e >> 10, code = e & 1023;
        const float* ep = ew + (size_t)code * DIM;
        const float* zr = &zrow[tk * 260];
        float s = 0.0f;
#pragma unroll 8
        for (int d = 0; d < DIM; d += 4) {
            float4 e4 = *reinterpret_cast<const float4*>(ep + d);
            float4 z4 = *reinterpret_cast<const float4*>(zr + d);
            s = fmaf(z4.x, e4.x, s);
            s = fmaf(z4.y, e4.y, s);
            s = fmaf(z4.z, e4.z, s);
            s = fmaf(z4.w, e4.w, s);
        }
        float dv = (zn[tok0 + tk] + en[code]) - 2.0f * s;
        unsigned long long key = ((unsigned long long)__float_as_uint(dv) << 32) | (unsigned)code;
        atomicMin(&best[tk], key);
    }
    __syncthreads();
    if (t < RS_TOK) out_idx[tok0 + t] = (float)(unsigned)(best[t] & 0x3FFu);
}

// ---------------------------------------------------------------------------
// one_hot: 33.5M floats (8B-aligned region -> float2 stores)
// ---------------------------------------------------------------------------
__global__ __launch_bounds__(256) void vq_onehot(const float* __restrict__ idxf,
                                                 float* __restrict__ oh)
{
    const unsigned stride = gridDim.x * blockDim.x;
    const unsigned total2 = N_TOK * (NE / 2);
    for (unsigned o2 = blockIdx.x * blockDim.x + threadIdx.x; o2 < total2; o2 += stride) {
        unsigned n = o2 >> 7;
        int k = (int)((o2 & 127u) << 1);
        int idx = (int)idxf[n];
        float2 v;
        v.x = (k == idx) ? 1.0f : 0.0f;
        v.y = (k + 1 == idx) ? 1.0f : 0.0f;
        reinterpret_cast<float2*>(oh)[o2] = v;
    }
}

// ---------------------------------------------------------------------------
// z_q gather + SSE accumulation (4B-aligned region -> scalar stores)
// ---------------------------------------------------------------------------
__global__ __launch_bounds__(256) void vq_gather(const float* __restrict__ z,
                                                 const float* __restrict__ ew,
                                                 const float* __restrict__ idxf,
                                                 float* __restrict__ zq,
                                                 float* __restrict__ sse)
{
    float part = 0.0f;
    const unsigned stride = gridDim.x * blockDim.x;
    const unsigned total = N_TOK * DIM;
    for (unsigned o = blockIdx.x * blockDim.x + threadIdx.x; o < total; o += stride) {
        unsigned w = o & 31u;
        unsigned h = (o >> 5) & 31u;
        unsigned c = (o >> 10) & 255u;
        unsigned b = o >> 18;
        unsigned n = (b << 10) + (h << 5) + w;
        int idx = (int)idxf[n];
        float q = ew[(size_t)idx * DIM + c];
        float zv = z[o];
        zq[o] = q;
        float dx = q - zv;
        part = fmaf(dx, dx, part);
    }
    __shared__ float red[256];
    red[threadIdx.x] = part;
    __syncthreads();
    for (int s = 128; s > 0; s >>= 1) {
        if ((int)threadIdx.x < s) red[threadIdx.x] += red[threadIdx.x + s];
        __syncthreads();
    }
    if (threadIdx.x == 0) atomicAdd(sse, red[0]);
}

// ---------------------------------------------------------------------------
// finalize: loss + perplexity (single block, LDS histogram)
// ---------------------------------------------------------------------------
__global__ __launch_bounds__(1024) void vq_finalize(const float* __restrict__ idxf,
                                                    const float* __restrict__ sse,
                                                    float* __restrict__ loss,
                                                    float* __restrict__ ppl)
{
    __shared__ int   hist[NE];
    __shared__ float red[NE];
    const int t = threadIdx.x;
    hist[t] = 0;
    __syncthreads();
    for (int i = t; i < N_TOK; i += 1024) {
        atomicAdd(&hist[(int)idxf[i]], 1);
    }
    __syncthreads();
    float p = (float)hist[t] * (1.0f / (float)N_TOK);
    red[t] = p * logf(p + 1e-10f);
    __syncthreads();
    for (int s = 512; s > 0; s >>= 1) {
        if (t < s) red[t] += red[t + s];
        __syncthreads();
    }
    if (t == 0) {
        ppl[0]  = expf(-red[0]);
        loss[0] = 0.25f * sse[0] / (float)(N_TOK * DIM);
    }
}

extern "C" void kernel_launch(void* const* d_in, const int* in_sizes, int n_in,
                              void* d_out, int out_size, void* d_ws, size_t ws_size,
                              hipStream_t stream)
{
    const float* z  = (const float*)d_in[0];   // (32,256,32,32)
    const float* ew = (const float*)d_in[1];   // (1024,256)
    float* out = (float*)d_out;
    float* wsf = (float*)d_ws;

    float* out_idx = out + OFF_IDX;
    float* out_oh  = out + OFF_OH;
    float* out_zq  = out + OFF_ZQ;
    float* out_ppl = out + OFF_PPL;

    char*  sc = (char*)out_oh;                 // scratch inside one_hot region
    float* ZN = (float*)(sc + ZN_B);
    float* EN = (float*)(sc + EN_B);
    unsigned long long* CM = (unsigned long long*)(sc + CM_B);

    vq_init<<<1, 1, 0, stream>>>(wsf);
    vq_zprep<<<512, 256, 0, stream>>>(z, sc, ZN);
    vq_eprep<<<4, 256, 0, stream>>>(ew, sc, EN);
    vq_argmin_mfma<<<2048, 256, 0, stream>>>(sc, ZN, EN, CM);
    vq_rescore<<<2048, 256, 0, stream>>>(sc, ew, ZN, EN, out_idx);
    vq_onehot<<<2048, 256, 0, stream>>>(out_idx, out_oh);
    vq_gather<<<2048, 256, 0, stream>>>(z, ew, out_idx, out_zq, wsf);
    vq_finalize<<<1, 1024, 0, stream>>>(out_idx, wsf, out, out_ppl);
}

// Round 7
// 193.726 us; speedup vs baseline: 2.6522x; 1.3804x over previous
//
#include <hip/hip_runtime.h>
#include <math.h>

// Problem constants
#define N_TOK 32768      // 32*32*32 tokens
#define NE    1024       // codebook size
#define DIM   256        // code dim
#define EPS   1.5e-3f    // candidate margin: 2-product prepass dist-err sigma ~3.8e-5 -> 20 sigma

// d_out layout (fp32 elements):
//  [0] loss | [1..8388609) z_q_st | [8388609] ppl | [8388610..+33554432) one_hot
//  | [41943042..+32768) indices (float)
#define OFF_ZQ   1u
#define OFF_PPL  8388609u
#define OFF_OH   8388610u
#define OFF_IDX  41943042u

// Scratch inside the one_hot output region (overwritten by vq_onehot later).
// Byte offsets relative to sc = (char*)(out + OFF_OH). oh base byte addr = 8 mod 16,
// so offsets = 8 mod 16 are absolutely 16B-aligned.
#define ZS_BYTES 16777216u            // one z-split: 32768*256*2B
#define ES_BYTES 524288u              // one e-split: 1024*256*2B
#define ZS0_B    8u
#define ZS1_B    (ZS0_B + ZS_BYTES)          // 16777224
#define ES0_B    (ZS0_B + 2u*ZS_BYTES)       // 33554440 (single e-split now)
#define ZT32_B   (ES0_B + 2u*ES_BYTES)       // 34603016: fp32 token-major z, 32 MB
#define CM_B     (ZT32_B + 33554432u)        // 68157448: cand masks, 32768*16 u64 = 4 MB
#define ZN_B     (CM_B + 4194304u)           // 72351752
#define EN_B     (ZN_B + 131072u)            // 72482824  (end < 134217728 OK)

typedef __attribute__((ext_vector_type(8))) short short8;
typedef __attribute__((ext_vector_type(8))) unsigned short ushort8;
typedef __attribute__((ext_vector_type(4))) float f32x4;

__device__ __forceinline__ unsigned short bf_rne(float f) {
    unsigned u = __float_as_uint(f);
    return (unsigned short)((u + 0x7FFFu + ((u >> 16) & 1u)) >> 16);
}
__device__ __forceinline__ float bf_tof(unsigned short h) {
    return __uint_as_float(((unsigned)h) << 16);
}
__device__ __forceinline__ void gload16(const void* g, void* l) {
    __builtin_amdgcn_global_load_lds((const __attribute__((address_space(1))) void*)g,
                                     (__attribute__((address_space(3))) void*)l, 16, 0, 0);
}

__global__ void vq_init(float* wsf) { wsf[0] = 0.0f; }

// ---------------------------------------------------------------------------
// z prep: transpose z[b][c][hw] -> token-major bf16 2-splits + fp32 copy, and
// zn[token] with the SAME fmaf order as round 2 (bit-identical).
// ---------------------------------------------------------------------------
__global__ __launch_bounds__(256) void vq_zprep(const float* __restrict__ z,
                                                char* __restrict__ sc,
                                                float* __restrict__ zn)
{
    __shared__ float zf[64 * 257];   // [hw][c] padded stride 257
    const int t = threadIdx.x;
    const int img = blockIdx.x >> 4;
    const int hw0 = (blockIdx.x & 15) << 6;
    const float* zb = z + (size_t)img * (DIM * 1024) + hw0;

#pragma unroll 4
    for (int it = 0; it < 64; ++it) {
        int idx = it * 256 + t;
        int c = idx >> 6, hw = idx & 63;
        zf[hw * 257 + c] = zb[(size_t)c * 1024 + hw];
    }
    __syncthreads();

    if (t < 64) {
        float s = 0.0f;
#pragma unroll 8
        for (int c = 0; c < DIM; ++c) { float v = zf[t * 257 + c]; s = fmaf(v, v, s); }
        zn[img * 1024 + hw0 + t] = s;
    }
    __syncthreads();

#pragma unroll
    for (int it = 0; it < 8; ++it) {
        int f = it * 256 + t;
        int tl = f >> 5, cg = f & 31;
        ushort8 s1, s2;
        float vv[8];
#pragma unroll
        for (int j = 0; j < 8; ++j) {
            float v = zf[tl * 257 + cg * 8 + j];
            vv[j] = v;
            unsigned short b1 = bf_rne(v); float r1 = v - bf_tof(b1);
            unsigned short b2 = bf_rne(r1);
            s1[j] = b1; s2[j] = b2;
        }
        int tok = img * 1024 + hw0 + tl;
        size_t eo = ((size_t)tok * 256 + cg * 8) * 2;
        *reinterpret_cast<ushort8*>(sc + ZS0_B + eo) = s1;
        *reinterpret_cast<ushort8*>(sc + ZS1_B + eo) = s2;
        size_t eo2 = ((size_t)tok * 256 + cg * 8) * 4;
        float4 f0 = make_float4(vv[0], vv[1], vv[2], vv[3]);
        float4 f1 = make_float4(vv[4], vv[5], vv[6], vv[7]);
        *reinterpret_cast<float4*>(sc + ZT32_B + eo2) = f0;
        *reinterpret_cast<float4*>(sc + ZT32_B + eo2 + 16) = f1;
    }
}

// ---------------------------------------------------------------------------
// e prep: single bf16 split of e_w + en (same fmaf order as round 2).
// ---------------------------------------------------------------------------
__global__ __launch_bounds__(256) void vq_eprep(const float* __restrict__ ew,
                                                char* __restrict__ sc,
                                                float* __restrict__ en)
{
    const int code = blockIdx.x * 256 + threadIdx.x;
    const float* p = ew + (size_t)code * DIM;
    float s = 0.0f;
    for (int dg = 0; dg < 32; ++dg) {
        ushort8 s1;
#pragma unroll
        for (int j = 0; j < 8; ++j) {
            float v = p[dg * 8 + j];
            s = fmaf(v, v, s);
            s1[j] = bf_rne(v);
        }
        size_t eo = ((size_t)code * 256 + dg * 8) * 2;
        *reinterpret_cast<ushort8*>(sc + ES0_B + eo) = s1;
    }
    en[code] = s;
}

// ---------------------------------------------------------------------------
// MFMA prepass: 128 tokens x 128 codes per block, 4 waves (2x2), BK=32,
// 2 products (z1*e1 + z2*e1): dist-err sigma ~3.8e-5 << EPS/2 = 7.5e-4.
// LDS 2 x 24KB -> 3 blocks/CU. XCD-bijective swizzle: all 8 cbi-siblings of
// an rb land on one XCD's L2 (z fetched from HBM once).
// Output: per-token 128-bit candidate mask (d <= blockmin + EPS) per block.
// ---------------------------------------------------------------------------
__global__ __launch_bounds__(256) void vq_argmin_mfma(const char* __restrict__ sc,
                                                      const float* __restrict__ zn,
                                                      const float* __restrict__ en,
                                                      unsigned long long* __restrict__ cmu)
{
    __shared__ short lds[2][12288];   // 2 x 24KB: za0, za1, eb0 each [128][32]

    const int t = threadIdx.x;
    const int lane = t & 63, w = t >> 6;
    const int wr = w >> 1, wc = w & 1;
    const int bid = (blockIdx.x & 7) * 256 + (blockIdx.x >> 3);   // XCD swizzle (2048 % 8 == 0)
    const int rb = bid >> 3, cbi = bid & 7;
    const int r0 = rb * 128, c0 = cbi * 128;

    unsigned srcoff[6];
#pragma unroll
    for (int i = 0; i < 6; ++i) {
        int flat = (w * 6 + i) * 64 + lane;    // 16B-slot id 0..1535
        int arr = flat >> 9;                    // 0,1 = z-splits; 2 = e-split
        int rr  = (flat & 511) >> 2;            // row 0..127
        int sl  = flat & 3;                     // physical k-slot
        int slx = sl ^ ((rr >> 1) & 3);         // source k-slot (pre-swizzle)
        unsigned off;
        if (arr == 0)      off = ZS0_B + (unsigned)(((r0 + rr) * 256 + slx * 8) * 2);
        else if (arr == 1) off = ZS1_B + (unsigned)(((r0 + rr) * 256 + slx * 8) * 2);
        else               off = ES0_B + (unsigned)(((c0 + rr) * 256 + slx * 8) * 2);
        srcoff[i] = off;
    }

    f32x4 acc[4][4];
#pragma unroll
    for (int i = 0; i < 4; ++i)
#pragma unroll
        for (int j = 0; j < 4; ++j) acc[i][j] = (f32x4)0.0f;

#pragma unroll
    for (int i = 0; i < 6; ++i)
        gload16(sc + srcoff[i], &lds[0][(w * 6 + i) * 512]);
    __syncthreads();

    int cur = 0;
    for (int kc = 0; kc < 8; ++kc) {
        if (kc < 7) {
            const unsigned kadd = (unsigned)(kc + 1) * 64u;   // +32 bf16 per chunk
#pragma unroll
            for (int i = 0; i < 6; ++i)
                gload16(sc + srcoff[i] + kadd, &lds[cur ^ 1][(w * 6 + i) * 512]);
        }
        const short* L = &lds[cur][0];
        const short* za0 = L;
        const short* za1 = L + 4096;
        const short* eb0 = L + 8192;

        short8 bfr0[4];
#pragma unroll
        for (int fn = 0; fn < 4; ++fn) {
            int row = wc * 64 + fn * 16 + (lane & 15);
            int slot = (lane >> 4) ^ ((row >> 1) & 3);
            bfr0[fn] = *reinterpret_cast<const short8*>(eb0 + row * 32 + slot * 8);
        }
#pragma unroll
        for (int fm = 0; fm < 4; ++fm) {
            int row = wr * 64 + fm * 16 + (lane & 15);
            int slot = (lane >> 4) ^ ((row >> 1) & 3);
            short8 a0 = *reinterpret_cast<const short8*>(za0 + row * 32 + slot * 8);
            short8 a1 = *reinterpret_cast<const short8*>(za1 + row * 32 + slot * 8);
#pragma unroll
            for (int fn = 0; fn < 4; ++fn) {
                acc[fm][fn] = __builtin_amdgcn_mfma_f32_16x16x32_bf16(a0, bfr0[fn], acc[fm][fn], 0, 0, 0);
                acc[fm][fn] = __builtin_amdgcn_mfma_f32_16x16x32_bf16(a1, bfr0[fn], acc[fm][fn], 0, 0, 0);
            }
        }
        __syncthreads();
        cur ^= 1;
    }

    // ---- epilogue phase 1: per-row block-min (cross-wave merged, race-free)
    float env[4];
#pragma unroll
    for (int fn = 0; fn < 4; ++fn)
        env[fn] = en[c0 + wc * 64 + fn * 16 + (lane & 15)];

    float* sdm = reinterpret_cast<float*>(&lds[0][0]);   // [2][128]

#pragma unroll
    for (int fm = 0; fm < 4; ++fm) {
#pragma unroll
        for (int reg = 0; reg < 4; ++reg) {
            int lrow = wr * 64 + fm * 16 + ((lane >> 4) << 2) + reg;
            float znv = zn[r0 + lrow];
            float bd = 3.0e38f;
#pragma unroll
            for (int fn = 0; fn < 4; ++fn) {
                float dv = (znv + env[fn]) - 2.0f * acc[fm][fn][reg];
                bd = fminf(bd, dv);
            }
#pragma unroll
            for (int m = 1; m <= 8; m <<= 1)
                bd = fminf(bd, __shfl_xor(bd, m));
            if ((lane & 15) == 0) sdm[wc * 128 + lrow] = bd;
        }
    }
    __syncthreads();
    if (t < 128) sdm[t] = fminf(sdm[t], sdm[128 + t]) + EPS;   // threshold per row
    __syncthreads();

    // ---- epilogue phase 2: ballot candidates, assemble 64-bit half-masks
#pragma unroll
    for (int fm = 0; fm < 4; ++fm) {
        unsigned long long bl[4][4];
#pragma unroll
        for (int fn = 0; fn < 4; ++fn) {
#pragma unroll
            for (int reg = 0; reg < 4; ++reg) {
                int lrow = wr * 64 + fm * 16 + ((lane >> 4) << 2) + reg;
                float thr = sdm[lrow];
                float dv = (zn[r0 + lrow] + env[fn]) - 2.0f * acc[fm][fn][reg];
                bl[fn][reg] = __ballot(dv <= thr);
            }
        }
        const int q = lane >> 4;
#pragma unroll
        for (int reg = 0; reg < 4; ++reg) {
            unsigned long long h =
                  ((bl[0][reg] >> (q * 16)) & 0xFFFFull)
                | (((bl[1][reg] >> (q * 16)) & 0xFFFFull) << 16)
                | (((bl[2][reg] >> (q * 16)) & 0xFFFFull) << 32)
                | (((bl[3][reg] >> (q * 16)) & 0xFFFFull) << 48);
            if ((lane & 15) == reg) {
                int row = wr * 64 + fm * 16 + q * 4 + reg;
                cmu[(size_t)(r0 + row) * 16 + cbi * 2 + wc] = h;
            }
        }
    }
}

// ---------------------------------------------------------------------------
// Exact rescore + fused z_q gather + SSE. One block = 16 tokens. Threads own
// (token, mask-word) pairs; prefix-scan builds a compact worklist; each thread
// rescores one pair with the round-2-exact ascending-d fmaf chain. Per-token
// lexicographic (d, idx) min via packed u64 LDS atomicMin. Then the block
// writes z_q rows (store-coalesced 64B segments) and accumulates SSE from the
// LDS-resident z rows — replaces the separate vq_gather kernel.
// ---------------------------------------------------------------------------
#define RS_TOK 16
#define RS_CAP 4096

__global__ __launch_bounds__(256) void vq_rescore(const char* __restrict__ sc,
                                                  const float* __restrict__ ew,
                                                  const float* __restrict__ zn,
                                                  const float* __restrict__ en,
                                                  float* __restrict__ out_idx,
                                                  float* __restrict__ zq,
                                                  float* __restrict__ sse)
{
    __shared__ float zrow[RS_TOK * 260];            // 16.6 KB, float4-aligned rows
    __shared__ int   wl[RS_CAP];                    // 16 KB worklist: (tok<<10)|code
    __shared__ int   cnt[256];                      // scan buffer (reused as SSE reduce)
    __shared__ unsigned long long best[RS_TOK];

    const int t = threadIdx.x;
    const int tok0 = blockIdx.x * RS_TOK;

    const unsigned long long* cmu = reinterpret_cast<const unsigned long long*>(sc + CM_B);
    const float* zt32 = reinterpret_cast<const float*>(sc + ZT32_B);

    // stage 16 z-rows (fp32), float4
#pragma unroll
    for (int i = 0; i < 4; ++i) {
        int f = i * 256 + t;                        // 1024 float4 slots
        int tk = f >> 6, d4 = f & 63;
        *reinterpret_cast<float4*>(&zrow[tk * 260 + d4 * 4]) =
            *reinterpret_cast<const float4*>(zt32 + (size_t)(tok0 + tk) * 256 + d4 * 4);
    }
    if (t < RS_TOK) best[t] = ~0ull;

    // one mask word per thread: tok = t>>4, wd = t&15
    unsigned long long v = cmu[(size_t)(tok0 + (t >> 4)) * 16 + (t & 15)];
    int myc = __popcll(v);
    cnt[t] = myc;
    __syncthreads();
    // inclusive Hillis-Steele scan over 256
    for (int st = 1; st < 256; st <<= 1) {
        int x = cnt[t];
        int y = (t >= st) ? cnt[t - st] : 0;
        __syncthreads();
        cnt[t] = x + y;
        __syncthreads();
    }
    int base = cnt[t] - myc;                        // exclusive prefix
    int total = cnt[255];
    // expand set bits into worklist
    {
        const int wd = t & 15, tk = t >> 4;
        unsigned long long vv = v;
        while (vv) {
            int b = __ffsll((long long)vv) - 1;
            vv &= vv - 1;
            int code = (wd >> 1) * 128 + (wd & 1) * 64 + b;
            if (base < RS_CAP) wl[base] = (tk << 10) | code;
            ++base;
        }
    }
    __syncthreads();
    if (total > RS_CAP) total = RS_CAP;

    for (int p = t; p < total; p += 256) {
        int e = wl[p];
        int tk = e >> 10, code = e & 1023;
        const float* ep = ew + (size_t)code * DIM;
        const float* zr = &zrow[tk * 260];
        float s = 0.0f;
#pragma unroll 8
        for (int d = 0; d < DIM; d += 4) {
            float4 e4 = *reinterpret_cast<const float4*>(ep + d);
            float4 z4 = *reinterpret_cast<const float4*>(zr + d);
            s = fmaf(z4.x, e4.x, s);
            s = fmaf(z4.y, e4.y, s);
            s = fmaf(z4.z, e4.z, s);
            s = fmaf(z4.w, e4.w, s);
        }
        float dv = (zn[tok0 + tk] + en[code]) - 2.0f * s;
        unsigned long long key = ((unsigned long long)__float_as_uint(dv) << 32) | (unsigned)code;
        atomicMin(&best[tk], key);
    }
    __syncthreads();
    if (t < RS_TOK) out_idx[tok0 + t] = (float)(unsigned)(best[t] & 0x3FFu);

    // ---- fused z_q gather + SSE (z rows already in LDS)
    const int tk2 = t & 15, cg2 = t >> 4;
    const int bidx = (int)(best[tk2] & 0x3FFu);
    const int img = tok0 >> 10;
    const int hwp = (tok0 & 1023) + tk2;
    float part = 0.0f;
    float* zqb = zq + (size_t)img * (DIM * 1024) + hwp;
    const float* ewb = ew + (size_t)bidx * DIM;
#pragma unroll
    for (int i = 0; i < 16; ++i) {
        int c = cg2 * 16 + i;
        float q = ewb[c];
        float zv = zrow[tk2 * 260 + c];
        zqb[(size_t)c << 10] = q;                  // lanes 0..15 -> 64B segments
        float dx = q - zv;
        part = fmaf(dx, dx, part);
    }
    float* redf = reinterpret_cast<float*>(cnt);
    redf[t] = part;
    __syncthreads();
    for (int s2 = 128; s2 > 0; s2 >>= 1) {
        if (t < s2) redf[t] += redf[t + s2];
        __syncthreads();
    }
    if (t == 0) atomicAdd(sse, redf[0]);
}

// ---------------------------------------------------------------------------
// one_hot: 33.5M floats (8B-aligned region -> float2 stores)
// ---------------------------------------------------------------------------
__global__ __launch_bounds__(256) void vq_onehot(const float* __restrict__ idxf,
                                                 float* __restrict__ oh)
{
    const unsigned stride = gridDim.x * blockDim.x;
    const unsigned total2 = N_TOK * (NE / 2);
    for (unsigned o2 = blockIdx.x * blockDim.x + threadIdx.x; o2 < total2; o2 += stride) {
        unsigned n = o2 >> 7;
        int k = (int)((o2 & 127u) << 1);
        int idx = (int)idxf[n];
        float2 v;
        v.x = (k == idx) ? 1.0f : 0.0f;
        v.y = (k + 1 == idx) ? 1.0f : 0.0f;
        reinterpret_cast<float2*>(oh)[o2] = v;
    }
}

// ---------------------------------------------------------------------------
// finalize: loss + perplexity (single block, LDS histogram, float2 loads)
// ---------------------------------------------------------------------------
__global__ __launch_bounds__(1024) void vq_finalize(const float* __restrict__ idxf,
                                                    const float* __restrict__ sse,
                                                    float* __restrict__ loss,
                                                    float* __restrict__ ppl)
{
    __shared__ int   hist[NE];
    __shared__ float red[NE];
    const int t = threadIdx.x;
    hist[t] = 0;
    __syncthreads();
    const float2* idx2 = reinterpret_cast<const float2*>(idxf);
    for (int i = t; i < N_TOK / 2; i += 1024) {
        float2 v = idx2[i];
        atomicAdd(&hist[(int)v.x], 1);
        atomicAdd(&hist[(int)v.y], 1);
    }
    __syncthreads();
    float p = (float)hist[t] * (1.0f / (float)N_TOK);
    red[t] = p * logf(p + 1e-10f);
    __syncthreads();
    for (int s = 512; s > 0; s >>= 1) {
        if (t < s) red[t] += red[t + s];
        __syncthreads();
    }
    if (t == 0) {
        ppl[0]  = expf(-red[0]);
        loss[0] = 0.25f * sse[0] / (float)(N_TOK * DIM);
    }
}

extern "C" void kernel_launch(void* const* d_in, const int* in_sizes, int n_in,
                              void* d_out, int out_size, void* d_ws, size_t ws_size,
                              hipStream_t stream)
{
    const float* z  = (const float*)d_in[0];   // (32,256,32,32)
    const float* ew = (const float*)d_in[1];   // (1024,256)
    float* out = (float*)d_out;
    float* wsf = (float*)d_ws;

    float* out_idx = out + OFF_IDX;
    float* out_oh  = out + OFF_OH;
    float* out_zq  = out + OFF_ZQ;
    float* out_ppl = out + OFF_PPL;

    char*  sc = (char*)out_oh;                 // scratch inside one_hot region
    float* ZN = (float*)(sc + ZN_B);
    float* EN = (float*)(sc + EN_B);
    unsigned long long* CM = (unsigned long long*)(sc + CM_B);

    vq_init<<<1, 1, 0, stream>>>(wsf);
    vq_zprep<<<512, 256, 0, stream>>>(z, sc, ZN);
    vq_eprep<<<4, 256, 0, stream>>>(ew, sc, EN);
    vq_argmin_mfma<<<2048, 256, 0, stream>>>(sc, ZN, EN, CM);
    vq_rescore<<<2048, 256, 0, stream>>>(sc, ew, ZN, EN, out_idx, out_zq, wsf);
    vq_onehot<<<2048, 256, 0, stream>>>(out_idx, out_oh);
    vq_finalize<<<1, 1024, 0, stream>>>(out_idx, wsf, out, out_ppl);
}

// Round 8
// 146.473 us; speedup vs baseline: 3.5078x; 1.3226x over previous
//
#include <hip/hip_runtime.h>
#include <math.h>

// Problem constants
#define N_TOK 32768      // 32*32*32 tokens
#define NE    1024       // codebook size
#define DIM   256        // code dim
#define EPS   1.5e-3f    // candidate margin: 1-product prepass dist-err sigma ~3e-5 -> ~50 sigma

// d_out layout (fp32 elements):
//  [0] loss | [1..8388609) z_q_st | [8388609] ppl | [8388610..+33554432) one_hot
//  | [41943042..+32768) indices (float)
#define OFF_ZQ   1u
#define OFF_PPL  8388609u
#define OFF_OH   8388610u
#define OFF_IDX  41943042u

#define RS_CAP 4096

typedef __attribute__((ext_vector_type(8))) short short8;
typedef __attribute__((ext_vector_type(8))) unsigned short ushort8;
typedef __attribute__((ext_vector_type(4))) float f32x4;

__device__ __forceinline__ unsigned short bf_rne(float f) {
    unsigned u = __float_as_uint(f);
    return (unsigned short)((u + 0x7FFFu + ((u >> 16) & 1u)) >> 16);
}
__device__ __forceinline__ void gload16(const void* g, void* l) {
    __builtin_amdgcn_global_load_lds((const __attribute__((address_space(1))) void*)g,
                                     (__attribute__((address_space(3))) void*)l, 16, 0, 0);
}

__global__ void vq_init(float* sse) { sse[0] = 0.0f; }

// ---------------------------------------------------------------------------
// z prep: transpose z[b][c][hw] -> token-major bf16 split z1[token][c] and
// zn[token] with the SAME fmaf order as round 2 (bit-identical).
// ---------------------------------------------------------------------------
__global__ __launch_bounds__(256) void vq_zprep(const float* __restrict__ z,
                                                unsigned short* __restrict__ z1,
                                                float* __restrict__ zn)
{
    __shared__ float zf[64 * 257];   // [hw][c] padded stride 257
    const int t = threadIdx.x;
    const int img = blockIdx.x >> 4;
    const int hw0 = (blockIdx.x & 15) << 6;
    const float* zb = z + (size_t)img * (DIM * 1024) + hw0;

#pragma unroll 4
    for (int it = 0; it < 64; ++it) {
        int idx = it * 256 + t;
        int c = idx >> 6, hw = idx & 63;
        zf[hw * 257 + c] = zb[(size_t)c * 1024 + hw];
    }
    __syncthreads();

    if (t < 64) {
        float s = 0.0f;
#pragma unroll 8
        for (int c = 0; c < DIM; ++c) { float v = zf[t * 257 + c]; s = fmaf(v, v, s); }
        zn[img * 1024 + hw0 + t] = s;
    }
    __syncthreads();

#pragma unroll
    for (int it = 0; it < 8; ++it) {
        int f = it * 256 + t;
        int tl = f >> 5, cg = f & 31;
        ushort8 s1;
#pragma unroll
        for (int j = 0; j < 8; ++j) s1[j] = bf_rne(zf[tl * 257 + cg * 8 + j]);
        int tok = img * 1024 + hw0 + tl;
        *reinterpret_cast<ushort8*>(z1 + (size_t)tok * 256 + cg * 8) = s1;
    }
}

// ---------------------------------------------------------------------------
// e prep: single bf16 split of e_w + en (same fmaf order as round 2).
// ---------------------------------------------------------------------------
__global__ __launch_bounds__(256) void vq_eprep(const float* __restrict__ ew,
                                                unsigned short* __restrict__ e1,
                                                float* __restrict__ en)
{
    const int code = blockIdx.x * 256 + threadIdx.x;
    const float* p = ew + (size_t)code * DIM;
    float s = 0.0f;
    for (int dg = 0; dg < 32; ++dg) {
        ushort8 s1;
#pragma unroll
        for (int j = 0; j < 8; ++j) {
            float v = p[dg * 8 + j];
            s = fmaf(v, v, s);
            s1[j] = bf_rne(v);
        }
        *reinterpret_cast<ushort8*>(e1 + (size_t)code * 256 + dg * 8) = s1;
    }
    en[code] = s;
}

// ---------------------------------------------------------------------------
// MFMA prepass: 128 tokens x 128 codes per block, 4 waves (2x2), BK=32,
// 1 product (z1*e1). Per-row relative distance en - 2*dot (zn dropped: it is
// row-constant, so candidate selection is unchanged and values sit near 0
// where fp32 ulp is tiny). LDS 2 x 16KB -> ~5 blocks/CU. XCD-bijective
// swizzle keeps the 8 cbi-siblings of an rb on one XCD's L2.
// Output: per-token 128-bit candidate mask (d <= blockmin + EPS) per block.
// ---------------------------------------------------------------------------
__global__ __launch_bounds__(256) void vq_argmin_mfma(const unsigned short* __restrict__ z1,
                                                      const unsigned short* __restrict__ e1,
                                                      const float* __restrict__ en,
                                                      unsigned long long* __restrict__ cmu)
{
    __shared__ short lds[2][8192];   // per buf: za [0..4095], eb [4096..8191]

    const int t = threadIdx.x;
    const int lane = t & 63, w = t >> 6;
    const int wr = w >> 1, wc = w & 1;
    const int bid = (blockIdx.x & 7) * 256 + (blockIdx.x >> 3);   // XCD swizzle (2048 % 8 == 0)
    const int rb = bid >> 3, cbi = bid & 7;
    const int r0 = rb * 128, c0 = cbi * 128;

    const char* srcp[4];
#pragma unroll
    for (int i = 0; i < 4; ++i) {
        int flat = (w * 4 + i) * 64 + lane;    // 16B-slot id 0..1023
        int arr = flat >> 9;                    // 0 = z1, 1 = e1
        int rr  = (flat & 511) >> 2;            // row 0..127
        int sl  = flat & 3;                     // physical k-slot
        int slx = sl ^ ((rr >> 1) & 3);         // source k-slot (pre-swizzle)
        srcp[i] = (arr == 0)
            ? (const char*)(z1 + (size_t)(r0 + rr) * 256 + slx * 8)
            : (const char*)(e1 + (size_t)(c0 + rr) * 256 + slx * 8);
    }

    f32x4 acc[4][4];
#pragma unroll
    for (int i = 0; i < 4; ++i)
#pragma unroll
        for (int j = 0; j < 4; ++j) acc[i][j] = (f32x4)0.0f;

#pragma unroll
    for (int i = 0; i < 4; ++i)
        gload16(srcp[i], &lds[0][(w * 4 + i) * 512]);
    __syncthreads();

    int cur = 0;
    for (int kc = 0; kc < 8; ++kc) {
        if (kc < 7) {
            const unsigned kadd = (unsigned)(kc + 1) * 64u;   // +32 bf16 per chunk
#pragma unroll
            for (int i = 0; i < 4; ++i)
                gload16(srcp[i] + kadd, &lds[cur ^ 1][(w * 4 + i) * 512]);
        }
        const short* L = &lds[cur][0];
        const short* za = L;
        const short* eb = L + 4096;

        short8 bfr[4];
#pragma unroll
        for (int fn = 0; fn < 4; ++fn) {
            int row = wc * 64 + fn * 16 + (lane & 15);
            int slot = (lane >> 4) ^ ((row >> 1) & 3);
            bfr[fn] = *reinterpret_cast<const short8*>(eb + row * 32 + slot * 8);
        }
#pragma unroll
        for (int fm = 0; fm < 4; ++fm) {
            int row = wr * 64 + fm * 16 + (lane & 15);
            int slot = (lane >> 4) ^ ((row >> 1) & 3);
            short8 a0 = *reinterpret_cast<const short8*>(za + row * 32 + slot * 8);
#pragma unroll
            for (int fn = 0; fn < 4; ++fn)
                acc[fm][fn] = __builtin_amdgcn_mfma_f32_16x16x32_bf16(a0, bfr[fn], acc[fm][fn], 0, 0, 0);
        }
        __syncthreads();
        cur ^= 1;
    }

    // ---- epilogue phase 1: per-row block-min (cross-wave merged, race-free)
    float env[4];
#pragma unroll
    for (int fn = 0; fn < 4; ++fn)
        env[fn] = en[c0 + wc * 64 + fn * 16 + (lane & 15)];

    float* sdm = reinterpret_cast<float*>(&lds[0][0]);   // [2][128]

#pragma unroll
    for (int fm = 0; fm < 4; ++fm) {
#pragma unroll
        for (int reg = 0; reg < 4; ++reg) {
            int lrow = wr * 64 + fm * 16 + ((lane >> 4) << 2) + reg;
            float bd = 3.0e38f;
#pragma unroll
            for (int fn = 0; fn < 4; ++fn) {
                float dv = env[fn] - 2.0f * acc[fm][fn][reg];
                bd = fminf(bd, dv);
            }
#pragma unroll
            for (int m = 1; m <= 8; m <<= 1)
                bd = fminf(bd, __shfl_xor(bd, m));
            if ((lane & 15) == 0) sdm[wc * 128 + lrow] = bd;
        }
    }
    __syncthreads();
    if (t < 128) sdm[t] = fminf(sdm[t], sdm[128 + t]) + EPS;   // threshold per row
    __syncthreads();

    // ---- epilogue phase 2: ballot candidates, assemble 64-bit half-masks
#pragma unroll
    for (int fm = 0; fm < 4; ++fm) {
        unsigned long long bl[4][4];
#pragma unroll
        for (int fn = 0; fn < 4; ++fn) {
#pragma unroll
            for (int reg = 0; reg < 4; ++reg) {
                int lrow = wr * 64 + fm * 16 + ((lane >> 4) << 2) + reg;
                float thr = sdm[lrow];
                float dv = env[fn] - 2.0f * acc[fm][fn][reg];
                bl[fn][reg] = __ballot(dv <= thr);
            }
        }
        const int q = lane >> 4;
#pragma unroll
        for (int reg = 0; reg < 4; ++reg) {
            unsigned long long h =
                  ((bl[0][reg] >> (q * 16)) & 0xFFFFull)
                | (((bl[1][reg] >> (q * 16)) & 0xFFFFull) << 16)
                | (((bl[2][reg] >> (q * 16)) & 0xFFFFull) << 32)
                | (((bl[3][reg] >> (q * 16)) & 0xFFFFull) << 48);
            if ((lane & 15) == reg) {
                int row = wr * 64 + fm * 16 + q * 4 + reg;
                cmu[(size_t)(r0 + row) * 16 + cbi * 2 + wc] = h;
            }
        }
    }
}

// ---------------------------------------------------------------------------
// Exact rescore + fused z_q gather + SSE + (optional) fused one_hot writes.
// One block = 16 tokens. z rows staged straight from original z (64B-sector
// reads, LDS transpose). Worklist via prefix-scan; each thread rescores one
// (tok,code) with the round-2-exact ascending-d fmaf chain (formula identical
// to rounds 5-7). Per-token lexicographic (d, idx) min via packed u64 LDS
// atomicMin. If oh != null, the block also writes its 16 one_hot rows
// (float4 interior, float2 prefix/suffix for the 8-mod-16 base).
// ---------------------------------------------------------------------------
__global__ __launch_bounds__(256) void vq_rescore(const float* __restrict__ z,
                                                  const float* __restrict__ ew,
                                                  const float* __restrict__ zn,
                                                  const float* __restrict__ en,
                                                  const unsigned long long* __restrict__ cmu,
                                                  float* __restrict__ out_idx,
                                                  float* __restrict__ zq,
                                                  float* __restrict__ sse,
                                                  float* __restrict__ oh)
{
    __shared__ float zrow[16 * 260];                // 16.6 KB, float4-aligned rows
    __shared__ int   wl[RS_CAP];                    // 16 KB worklist: (tok<<10)|code
    __shared__ int   cnt[256];                      // scan buffer (reused as SSE reduce)
    __shared__ unsigned long long best[16];

    const int t = threadIdx.x;
    const int tok0 = blockIdx.x * 16;
    const int img = tok0 >> 10, hw0 = tok0 & 1023;

    // stage 16 z-rows from original z: lane owns channel c=t, 4 float4 along hw
    {
        const float* zc = z + (size_t)img * (DIM * 1024) + (size_t)t * 1024 + hw0;
#pragma unroll
        for (int j = 0; j < 4; ++j) {
            float4 v = *reinterpret_cast<const float4*>(zc + 4 * j);
            zrow[(4 * j + 0) * 260 + t] = v.x;
            zrow[(4 * j + 1) * 260 + t] = v.y;
            zrow[(4 * j + 2) * 260 + t] = v.z;
            zrow[(4 * j + 3) * 260 + t] = v.w;
        }
    }
    if (t < 16) best[t] = ~0ull;

    // one mask word per thread: tok = t>>4, wd = t&15
    unsigned long long v = cmu[(size_t)(tok0 + (t >> 4)) * 16 + (t & 15)];
    int myc = __popcll(v);
    cnt[t] = myc;
    __syncthreads();
    for (int st = 1; st < 256; st <<= 1) {          // inclusive Hillis-Steele scan
        int x = cnt[t];
        int y = (t >= st) ? cnt[t - st] : 0;
        __syncthreads();
        cnt[t] = x + y;
        __syncthreads();
    }
    int base = cnt[t] - myc;                        // exclusive prefix
    int total = cnt[255];
    {
        const int wd = t & 15, tk = t >> 4;
        unsigned long long vv = v;
        while (vv) {
            int b = __ffsll((long long)vv) - 1;
            vv &= vv - 1;
            int code = (wd >> 1) * 128 + (wd & 1) * 64 + b;
            if (base < RS_CAP) wl[base] = (tk << 10) | code;
            ++base;
        }
    }
    __syncthreads();
    if (total > RS_CAP) total = RS_CAP;

    for (int p = t; p < total; p += 256) {
        int e = wl[p];
        int tk = e >> 10, code = e & 1023;
        const float* ep = ew + (size_t)code * DIM;
        const float* zr = &zrow[tk * 260];
        float s = 0.0f;
#pragma unroll 8
        for (int d = 0; d < DIM; d += 4) {
            float4 e4 = *reinterpret_cast<const float4*>(ep + d);
            float4 z4 = *reinterpret_cast<const float4*>(zr + d);
            s = fmaf(z4.x, e4.x, s);
            s = fmaf(z4.y, e4.y, s);
            s = fmaf(z4.z, e4.z, s);
            s = fmaf(z4.w, e4.w, s);
        }
        float dv = (zn[tok0 + tk] + en[code]) - 2.0f * s;
        unsigned long long key = ((unsigned long long)__float_as_uint(dv) << 32) | (unsigned)code;
        atomicMin(&best[tk], key);
    }
    __syncthreads();
    if (t < 16) out_idx[tok0 + t] = (float)(unsigned)(best[t] & 0x3FFu);

    // ---- fused z_q gather + SSE (z rows already in LDS)
    const int tk2 = t & 15, cg2 = t >> 4;
    const int bidx = (int)(best[tk2] & 0x3FFu);
    const int hwp = hw0 + tk2;
    float part = 0.0f;
    float* zqb = zq + (size_t)img * (DIM * 1024) + hwp;
    const float* ewb = ew + (size_t)bidx * DIM;
#pragma unroll
    for (int i = 0; i < 16; ++i) {
        int c = cg2 * 16 + i;
        float q = ewb[c];
        float zv = zrow[tk2 * 260 + c];
        zqb[(size_t)c << 10] = q;                  // lanes 0..15 -> 64B segments
        float dx = q - zv;
        part = fmaf(dx, dx, part);
    }
    float* redf = reinterpret_cast<float*>(cnt);
    redf[t] = part;
    __syncthreads();
    for (int s2 = 128; s2 > 0; s2 >>= 1) {
        if (t < s2) redf[t] += redf[t + s2];
        __syncthreads();
    }
    if (t == 0) atomicAdd(sse, redf[0]);

    // ---- fused one_hot rows (only when scratch lives in d_ws)
    if (oh) {
        const int w2 = t >> 6, lane2 = t & 63;
#pragma unroll
        for (int rr = 0; rr < 4; ++rr) {
            const int row = w2 * 4 + rr;           // 0..15
            const int bi2 = (int)(best[row] & 0x3FFull);
            float* rowp = oh + (size_t)(tok0 + row) * 1024;
#pragma unroll
            for (int j = 0; j < 4; ++j) {
                int i4 = j * 64 + lane2;
                if (i4 < 254) {
                    int k = 2 + i4 * 4;            // k==2 mod 4 -> 16B-aligned abs addr
                    float4 vv4;
                    vv4.x = (k     == bi2) ? 1.0f : 0.0f;
                    vv4.y = (k + 1 == bi2) ? 1.0f : 0.0f;
                    vv4.z = (k + 2 == bi2) ? 1.0f : 0.0f;
                    vv4.w = (k + 3 == bi2) ? 1.0f : 0.0f;
                    *reinterpret_cast<float4*>(rowp + k) = vv4;
                }
            }
            if (lane2 == 0) {
                float2 v2; v2.x = (0 == bi2) ? 1.0f : 0.0f; v2.y = (1 == bi2) ? 1.0f : 0.0f;
                *reinterpret_cast<float2*>(rowp) = v2;
            } else if (lane2 == 1) {
                float2 v2; v2.x = (1022 == bi2) ? 1.0f : 0.0f; v2.y = (1023 == bi2) ? 1.0f : 0.0f;
                *reinterpret_cast<float2*>(rowp + 1022) = v2;
            }
        }
    }
}

// ---------------------------------------------------------------------------
// one_hot fallback kernel (scratch-in-oh path only): float2 stores
// ---------------------------------------------------------------------------
__global__ __launch_bounds__(256) void vq_onehot(const float* __restrict__ idxf,
                                                 float* __restrict__ oh)
{
    const unsigned stride = gridDim.x * blockDim.x;
    const unsigned total2 = N_TOK * (NE / 2);
    for (unsigned o2 = blockIdx.x * blockDim.x + threadIdx.x; o2 < total2; o2 += stride) {
        unsigned n = o2 >> 7;
        int k = (int)((o2 & 127u) << 1);
        int idx = (int)idxf[n];
        float2 v;
        v.x = (k == idx) ? 1.0f : 0.0f;
        v.y = (k + 1 == idx) ? 1.0f : 0.0f;
        reinterpret_cast<float2*>(oh)[o2] = v;
    }
}

// ---------------------------------------------------------------------------
// finalize: loss + perplexity (single block, LDS histogram, float2 loads)
// ---------------------------------------------------------------------------
__global__ __launch_bounds__(1024) void vq_finalize(const float* __restrict__ idxf,
                                                    const float* __restrict__ sse,
                                                    float* __restrict__ loss,
                                                    float* __restrict__ ppl)
{
    __shared__ int   hist[NE];
    __shared__ float red[NE];
    const int t = threadIdx.x;
    hist[t] = 0;
    __syncthreads();
    const float2* idx2 = reinterpret_cast<const float2*>(idxf);
    for (int i = t; i < N_TOK / 2; i += 1024) {
        float2 v = idx2[i];
        atomicAdd(&hist[(int)v.x], 1);
        atomicAdd(&hist[(int)v.y], 1);
    }
    __syncthreads();
    float p = (float)hist[t] * (1.0f / (float)N_TOK);
    red[t] = p * logf(p + 1e-10f);
    __syncthreads();
    for (int s = 512; s > 0; s >>= 1) {
        if (t < s) red[t] += red[t + s];
        __syncthreads();
    }
    if (t == 0) {
        ppl[0]  = expf(-red[0]);
        loss[0] = 0.25f * sse[0] / (float)(N_TOK * DIM);
    }
}

extern "C" void kernel_launch(void* const* d_in, const int* in_sizes, int n_in,
                              void* d_out, int out_size, void* d_ws, size_t ws_size,
                              hipStream_t stream)
{
    const float* z  = (const float*)d_in[0];   // (32,256,32,32)
    const float* ew = (const float*)d_in[1];   // (1024,256)
    float* out = (float*)d_out;

    float* out_idx = out + OFF_IDX;
    float* out_oh  = out + OFF_OH;
    float* out_zq  = out + OFF_ZQ;
    float* out_ppl = out + OFF_PPL;

    // Scratch placement: prefer d_ws (evidence: harness poison fills ~672 MB =
    // out 168 MB + ws ~500 MB). Fallback: inside the one_hot output region
    // (overwritten by vq_onehot afterwards). Offsets keep 16B absolute
    // alignment in both paths (oh base byte addr == 8 mod 16).
    const size_t need = 1024u + 33554432u + 524288u + 4194304u + 131072u + 4096u;
    const bool big = ws_size >= need && ws_size >= (size_t)48u * 1024u * 1024u;
    char* base = big ? (char*)d_ws : (char*)out_oh;
    const size_t Z1o = big ? 1024u : 8u;
    const size_t E1o = Z1o + 33554432u;
    const size_t CMo = E1o + 524288u;
    const size_t ZNo = CMo + 4194304u;
    const size_t ENo = ZNo + 131072u;

    unsigned short* Z1 = (unsigned short*)(base + Z1o);
    unsigned short* E1 = (unsigned short*)(base + E1o);
    unsigned long long* CM = (unsigned long long*)(base + CMo);
    float* ZN = (float*)(base + ZNo);
    float* EN = (float*)(base + ENo);
    float* SSE = (float*)d_ws;

    vq_init<<<1, 1, 0, stream>>>(SSE);
    vq_zprep<<<512, 256, 0, stream>>>(z, Z1, ZN);
    vq_eprep<<<4, 256, 0, stream>>>(ew, E1, EN);
    vq_argmin_mfma<<<2048, 256, 0, stream>>>(Z1, E1, EN, CM);
    vq_rescore<<<2048, 256, 0, stream>>>(z, ew, ZN, EN, CM, out_idx, out_zq, SSE,
                                         big ? out_oh : nullptr);
    if (!big) vq_onehot<<<2048, 256, 0, stream>>>(out_idx, out_oh);
    vq_finalize<<<1, 1024, 0, stream>>>(out_idx, SSE, out, out_ppl);
}

// Round 10
// 145.256 us; speedup vs baseline: 3.5372x; 1.0084x over previous
//
#include <hip/hip_runtime.h>
#include <math.h>

// Problem constants
#define N_TOK 32768      // 32*32*32 tokens
#define NE    1024       // codebook size
#define DIM   256        // code dim
#define EPS   1.5e-3f    // candidate margin: 1-product trunc-bf16 prepass err sigma ~4e-5 -> ~35 sigma

// d_out layout (fp32 elements):
//  [0] loss | [1..8388609) z_q_st | [8388609] ppl | [8388610..+33554432) one_hot
//  | [41943042..+32768) indices (float)
#define OFF_ZQ   1u
#define OFF_PPL  8388609u
#define OFF_OH   8388610u
#define OFF_IDX  41943042u

#define RS_CAP 4096

typedef __attribute__((ext_vector_type(8))) short short8;
typedef __attribute__((ext_vector_type(8))) unsigned short ushort8;
typedef __attribute__((ext_vector_type(4))) float f32x4;
typedef __attribute__((ext_vector_type(2))) float f32x2;

__device__ __forceinline__ unsigned short bf_rne(float f) {
    unsigned u = __float_as_uint(f);
    return (unsigned short)((u + 0x7FFFu + ((u >> 16) & 1u)) >> 16);
}
__device__ __forceinline__ void gload16(const void* g, void* l) {
    __builtin_amdgcn_global_load_lds((const __attribute__((address_space(1))) void*)g,
                                     (__attribute__((address_space(3))) void*)l, 16, 0, 0);
}

// ---------------------------------------------------------------------------
// Fused prep: blocks 0..511 = z-side (transpose + trunc-bf16 z1 + exact zn),
// blocks 512..515 = e-side (RNE bf16 e1 + exact en) + SSE zero.
// zn/en keep the SAME ascending-fmaf order as round 2 (bit-identical).
// ---------------------------------------------------------------------------
__global__ __launch_bounds__(256) void vq_prep(const float* __restrict__ z,
                                               const float* __restrict__ ew,
                                               unsigned short* __restrict__ z1,
                                               unsigned short* __restrict__ e1,
                                               float* __restrict__ zn,
                                               float* __restrict__ en,
                                               float* __restrict__ sse)
{
    __shared__ float zf[64 * 257];   // [hw][c] padded stride 257
    const int t = threadIdx.x;

    if (blockIdx.x >= 512) {
        // ---- e-side (4 blocks x 256 threads = 1024 codes)
        if (blockIdx.x == 512 && t == 0) sse[0] = 0.0f;
        const int code = (int)(blockIdx.x - 512) * 256 + t;
        const float* p = ew + (size_t)code * DIM;
        float s = 0.0f;
        for (int dg = 0; dg < 32; ++dg) {
            ushort8 s1;
#pragma unroll
            for (int j = 0; j < 8; ++j) {
                float v = p[dg * 8 + j];
                s = fmaf(v, v, s);
                s1[j] = bf_rne(v);
            }
            *reinterpret_cast<ushort8*>(e1 + (size_t)code * 256 + dg * 8) = s1;
        }
        en[code] = s;
        return;
    }

    // ---- z-side: 512 blocks = 32 images x 16 hw-tiles of 64
    const int img = blockIdx.x >> 4;
    const int hw0 = (blockIdx.x & 15) << 6;
    const float* zb = z + (size_t)img * (DIM * 1024) + hw0;

    // stage tile 64 hw x 256 c with float4 reads (coalesced along hw)
#pragma unroll
    for (int it = 0; it < 16; ++it) {
        int f = it * 256 + t;                 // 4096 float4 slots
        int c = f >> 4, hw4 = f & 15;
        float4 v = *reinterpret_cast<const float4*>(zb + (size_t)c * 1024 + hw4 * 4);
        zf[(hw4 * 4 + 0) * 257 + c] = v.x;
        zf[(hw4 * 4 + 1) * 257 + c] = v.y;
        zf[(hw4 * 4 + 2) * 257 + c] = v.z;
        zf[(hw4 * 4 + 3) * 257 + c] = v.w;
    }
    __syncthreads();

    // zn: c-ascending fmaf (bit-identical to round 2)
    if (t < 64) {
        float s = 0.0f;
#pragma unroll 8
        for (int c = 0; c < DIM; ++c) { float v = zf[t * 257 + c]; s = fmaf(v, v, s); }
        zn[img * 1024 + hw0 + t] = s;
    }
    // no barrier needed: the split phase only READS zf

    // trunc-bf16 split, token-major, coalesced 16B stores (prepass-only data)
#pragma unroll
    for (int it = 0; it < 8; ++it) {
        int f = it * 256 + t;
        int tl = f >> 5, cg = f & 31;
        ushort8 s1;
#pragma unroll
        for (int j = 0; j < 8; ++j)
            s1[j] = (unsigned short)(__float_as_uint(zf[tl * 257 + cg * 8 + j]) >> 16);
        int tok = img * 1024 + hw0 + tl;
        *reinterpret_cast<ushort8*>(z1 + (size_t)tok * 256 + cg * 8) = s1;
    }
}

// ---------------------------------------------------------------------------
// MFMA prepass: 128 tokens x 128 codes per block, 4 waves (2x2), BK=32,
// 1 product (z1*e1). Per-row relative distance en - 2*dot (zn dropped: it is
// row-constant, so candidate selection is unchanged). LDS 2 x 16KB.
// XCD-bijective swizzle keeps the 8 cbi-siblings of an rb on one XCD's L2.
// Output: per-token 128-bit candidate mask (d <= blockmin + EPS) per block.
// ---------------------------------------------------------------------------
__global__ __launch_bounds__(256) void vq_argmin_mfma(const unsigned short* __restrict__ z1,
                                                      const unsigned short* __restrict__ e1,
                                                      const float* __restrict__ en,
                                                      unsigned long long* __restrict__ cmu)
{
    __shared__ short lds[2][8192];   // per buf: za [0..4095], eb [4096..8191]

    const int t = threadIdx.x;
    const int lane = t & 63, w = t >> 6;
    const int wr = w >> 1, wc = w & 1;
    const int bid = (blockIdx.x & 7) * 256 + (blockIdx.x >> 3);   // XCD swizzle (2048 % 8 == 0)
    const int rb = bid >> 3, cbi = bid & 7;
    const int r0 = rb * 128, c0 = cbi * 128;

    const char* srcp[4];
#pragma unroll
    for (int i = 0; i < 4; ++i) {
        int flat = (w * 4 + i) * 64 + lane;    // 16B-slot id 0..1023
        int arr = flat >> 9;                    // 0 = z1, 1 = e1
        int rr  = (flat & 511) >> 2;            // row 0..127
        int sl  = flat & 3;                     // physical k-slot
        int slx = sl ^ ((rr >> 1) & 3);         // source k-slot (pre-swizzle)
        srcp[i] = (arr == 0)
            ? (const char*)(z1 + (size_t)(r0 + rr) * 256 + slx * 8)
            : (const char*)(e1 + (size_t)(c0 + rr) * 256 + slx * 8);
    }

    f32x4 acc[4][4];
#pragma unroll
    for (int i = 0; i < 4; ++i)
#pragma unroll
        for (int j = 0; j < 4; ++j) acc[i][j] = (f32x4)0.0f;

#pragma unroll
    for (int i = 0; i < 4; ++i)
        gload16(srcp[i], &lds[0][(w * 4 + i) * 512]);
    __syncthreads();

    int cur = 0;
    for (int kc = 0; kc < 8; ++kc) {
        if (kc < 7) {
            const unsigned kadd = (unsigned)(kc + 1) * 64u;   // +32 bf16 per chunk
#pragma unroll
            for (int i = 0; i < 4; ++i)
                gload16(srcp[i] + kadd, &lds[cur ^ 1][(w * 4 + i) * 512]);
        }
        const short* L = &lds[cur][0];
        const short* za = L;
        const short* eb = L + 4096;

        short8 bfr[4];
#pragma unroll
        for (int fn = 0; fn < 4; ++fn) {
            int row = wc * 64 + fn * 16 + (lane & 15);
            int slot = (lane >> 4) ^ ((row >> 1) & 3);
            bfr[fn] = *reinterpret_cast<const short8*>(eb + row * 32 + slot * 8);
        }
#pragma unroll
        for (int fm = 0; fm < 4; ++fm) {
            int row = wr * 64 + fm * 16 + (lane & 15);
            int slot = (lane >> 4) ^ ((row >> 1) & 3);
            short8 a0 = *reinterpret_cast<const short8*>(za + row * 32 + slot * 8);
#pragma unroll
            for (int fn = 0; fn < 4; ++fn)
                acc[fm][fn] = __builtin_amdgcn_mfma_f32_16x16x32_bf16(a0, bfr[fn], acc[fm][fn], 0, 0, 0);
        }
        __syncthreads();
        cur ^= 1;
    }

    // ---- epilogue phase 1: per-row block-min (cross-wave merged, race-free)
    float env[4];
#pragma unroll
    for (int fn = 0; fn < 4; ++fn)
        env[fn] = en[c0 + wc * 64 + fn * 16 + (lane & 15)];

    float* sdm = reinterpret_cast<float*>(&lds[0][0]);   // [2][128]

#pragma unroll
    for (int fm = 0; fm < 4; ++fm) {
#pragma unroll
        for (int reg = 0; reg < 4; ++reg) {
            int lrow = wr * 64 + fm * 16 + ((lane >> 4) << 2) + reg;
            float bd = 3.0e38f;
#pragma unroll
            for (int fn = 0; fn < 4; ++fn) {
                float dv = env[fn] - 2.0f * acc[fm][fn][reg];
                bd = fminf(bd, dv);
            }
#pragma unroll
            for (int m = 1; m <= 8; m <<= 1)
                bd = fminf(bd, __shfl_xor(bd, m));
            if ((lane & 15) == 0) sdm[wc * 128 + lrow] = bd;
        }
    }
    __syncthreads();
    if (t < 128) sdm[t] = fminf(sdm[t], sdm[128 + t]) + EPS;   // threshold per row
    __syncthreads();

    // ---- epilogue phase 2: ballot candidates, assemble 64-bit half-masks
#pragma unroll
    for (int fm = 0; fm < 4; ++fm) {
        unsigned long long bl[4][4];
#pragma unroll
        for (int fn = 0; fn < 4; ++fn) {
#pragma unroll
            for (int reg = 0; reg < 4; ++reg) {
                int lrow = wr * 64 + fm * 16 + ((lane >> 4) << 2) + reg;
                float thr = sdm[lrow];
                float dv = env[fn] - 2.0f * acc[fm][fn][reg];
                bl[fn][reg] = __ballot(dv <= thr);
            }
        }
        const int q = lane >> 4;
#pragma unroll
        for (int reg = 0; reg < 4; ++reg) {
            unsigned long long h =
                  ((bl[0][reg] >> (q * 16)) & 0xFFFFull)
                | (((bl[1][reg] >> (q * 16)) & 0xFFFFull) << 16)
                | (((bl[2][reg] >> (q * 16)) & 0xFFFFull) << 32)
                | (((bl[3][reg] >> (q * 16)) & 0xFFFFull) << 48);
            if ((lane & 15) == reg) {
                int row = wr * 64 + fm * 16 + q * 4 + reg;
                cmu[(size_t)(r0 + row) * 16 + cbi * 2 + wc] = h;
            }
        }
    }
}

// ---------------------------------------------------------------------------
// Exact rescore + fused z_q gather + SSE + (optional) fused one_hot writes.
// One block = 16 tokens. Wave-shfl scan (1 barrier) builds the worklist; each
// thread rescores one (tok,code) with the round-2-exact ascending-d fmaf
// chain (formula identical to rounds 5-8). Per-token lexicographic (d, idx)
// min via packed u64 LDS atomicMin. Terminal z_q / one_hot stores are
// nontemporal (ext-vector types). one_hot coverage fix: i4 < 255.
// ---------------------------------------------------------------------------
__global__ __launch_bounds__(256) void vq_rescore(const float* __restrict__ z,
                                                  const float* __restrict__ ew,
                                                  const float* __restrict__ zn,
                                                  const float* __restrict__ en,
                                                  const unsigned long long* __restrict__ cmu,
                                                  float* __restrict__ out_idx,
                                                  float* __restrict__ zq,
                                                  float* __restrict__ sse,
                                                  float* __restrict__ oh)
{
    __shared__ float zrow[16 * 260];                // 16.6 KB, float4-aligned rows
    __shared__ int   wl[RS_CAP];                    // 16 KB worklist: (tok<<10)|code
    __shared__ int   wsum[4];
    __shared__ float redf[256];
    __shared__ unsigned long long best[16];

    const int t = threadIdx.x, lane = t & 63, w = t >> 6;
    const int tok0 = blockIdx.x * 16;
    const int img = tok0 >> 10, hw0 = tok0 & 1023;

    // stage 16 z-rows from original z: lane owns channel c=t, 4 float4 along hw
    {
        const float* zc = z + (size_t)img * (DIM * 1024) + (size_t)t * 1024 + hw0;
#pragma unroll
        for (int j = 0; j < 4; ++j) {
            float4 v = *reinterpret_cast<const float4*>(zc + 4 * j);
            zrow[(4 * j + 0) * 260 + t] = v.x;
            zrow[(4 * j + 1) * 260 + t] = v.y;
            zrow[(4 * j + 2) * 260 + t] = v.z;
            zrow[(4 * j + 3) * 260 + t] = v.w;
        }
    }
    if (t < 16) best[t] = ~0ull;

    // one mask word per thread: tok = t>>4, wd = t&15; wave-shfl scan
    unsigned long long v = cmu[(size_t)(tok0 + (t >> 4)) * 16 + (t & 15)];
    int myc = __popcll(v);
    int x = myc;
#pragma unroll
    for (int d = 1; d < 64; d <<= 1) {
        int y = __shfl_up(x, d);
        if (lane >= d) x += y;
    }
    if (lane == 63) wsum[w] = x;
    __syncthreads();
    int woff = 0;
#pragma unroll
    for (int i = 0; i < 4; ++i) woff += (i < w) ? wsum[i] : 0;
    int total = wsum[0] + wsum[1] + wsum[2] + wsum[3];
    int base = woff + x - myc;                      // global exclusive prefix
    {
        const int wd = t & 15, tk = t >> 4;
        unsigned long long vv = v;
        while (vv) {
            int b = __ffsll((long long)vv) - 1;
            vv &= vv - 1;
            int code = (wd >> 1) * 128 + (wd & 1) * 64 + b;
            if (base < RS_CAP) wl[base] = (tk << 10) | code;
            ++base;
        }
    }
    __syncthreads();
    if (total > RS_CAP) total = RS_CAP;

    for (int p = t; p < total; p += 256) {
        int e = wl[p];
        int tk = e >> 10, code = e & 1023;
        const float* ep = ew + (size_t)code * DIM;
        const float* zr = &zrow[tk * 260];
        float s = 0.0f;
#pragma unroll 8
        for (int d = 0; d < DIM; d += 4) {
            float4 e4 = *reinterpret_cast<const float4*>(ep + d);
            float4 z4 = *reinterpret_cast<const float4*>(zr + d);
            s = fmaf(z4.x, e4.x, s);
            s = fmaf(z4.y, e4.y, s);
            s = fmaf(z4.z, e4.z, s);
            s = fmaf(z4.w, e4.w, s);
        }
        float dv = (zn[tok0 + tk] + en[code]) - 2.0f * s;
        unsigned long long key = ((unsigned long long)__float_as_uint(dv) << 32) | (unsigned)code;
        atomicMin(&best[tk], key);
    }
    __syncthreads();
    if (t < 16) out_idx[tok0 + t] = (float)(unsigned)(best[t] & 0x3FFu);

    // ---- fused z_q gather + SSE (z rows already in LDS); nontemporal stores
    const int tk2 = t & 15, cg2 = t >> 4;
    const int bidx = (int)(best[tk2] & 0x3FFu);
    const int hwp = hw0 + tk2;
    float part = 0.0f;
    float* zqb = zq + (size_t)img * (DIM * 1024) + hwp;
    const float* ewb = ew + (size_t)bidx * DIM;
#pragma unroll
    for (int i = 0; i < 16; ++i) {
        int c = cg2 * 16 + i;
        float q = ewb[c];
        float zv = zrow[tk2 * 260 + c];
        __builtin_nontemporal_store(q, &zqb[(size_t)c << 10]);   // 64B segments
        float dx = q - zv;
        part = fmaf(dx, dx, part);
    }
    redf[t] = part;
    __syncthreads();
    for (int s2 = 128; s2 > 0; s2 >>= 1) {
        if (t < s2) redf[t] += redf[t + s2];
        __syncthreads();
    }
    if (t == 0) atomicAdd(sse, redf[0]);

    // ---- fused one_hot rows (only when scratch lives in d_ws)
    if (oh) {
        const int w2 = t >> 6, lane2 = t & 63;
#pragma unroll
        for (int rr = 0; rr < 4; ++rr) {
            const int row = w2 * 4 + rr;           // 0..15
            const int bi2 = (int)(best[row] & 0x3FFull);
            float* rowp = oh + (size_t)(tok0 + row) * 1024;
#pragma unroll
            for (int j = 0; j < 4; ++j) {
                int i4 = j * 64 + lane2;
                if (i4 < 255) {                    // k = 2..1018 -> covers 2..1021
                    int k = 2 + i4 * 4;            // abs addr 16B-aligned (base = 8 mod 16)
                    f32x4 vv4;
                    vv4.x = (k     == bi2) ? 1.0f : 0.0f;
                    vv4.y = (k + 1 == bi2) ? 1.0f : 0.0f;
                    vv4.z = (k + 2 == bi2) ? 1.0f : 0.0f;
                    vv4.w = (k + 3 == bi2) ? 1.0f : 0.0f;
                    __builtin_nontemporal_store(vv4, reinterpret_cast<f32x4*>(rowp + k));
                }
            }
            if (lane2 == 0) {
                f32x2 v2; v2.x = (0 == bi2) ? 1.0f : 0.0f; v2.y = (1 == bi2) ? 1.0f : 0.0f;
                __builtin_nontemporal_store(v2, reinterpret_cast<f32x2*>(rowp));
            } else if (lane2 == 1) {
                f32x2 v2; v2.x = (1022 == bi2) ? 1.0f : 0.0f; v2.y = (1023 == bi2) ? 1.0f : 0.0f;
                __builtin_nontemporal_store(v2, reinterpret_cast<f32x2*>(rowp + 1022));
            }
        }
    }
}

// ---------------------------------------------------------------------------
// one_hot fallback kernel (scratch-in-oh path only): float2 stores
// ---------------------------------------------------------------------------
__global__ __launch_bounds__(256) void vq_onehot(const float* __restrict__ idxf,
                                                 float* __restrict__ oh)
{
    const unsigned stride = gridDim.x * blockDim.x;
    const unsigned total2 = N_TOK * (NE / 2);
    for (unsigned o2 = blockIdx.x * blockDim.x + threadIdx.x; o2 < total2; o2 += stride) {
        unsigned n = o2 >> 7;
        int k = (int)((o2 & 127u) << 1);
        int idx = (int)idxf[n];
        float2 v;
        v.x = (k == idx) ? 1.0f : 0.0f;
        v.y = (k + 1 == idx) ? 1.0f : 0.0f;
        reinterpret_cast<float2*>(oh)[o2] = v;
    }
}

// ---------------------------------------------------------------------------
// finalize: loss + perplexity (single block, LDS histogram, float2 loads)
// ---------------------------------------------------------------------------
__global__ __launch_bounds__(1024) void vq_finalize(const float* __restrict__ idxf,
                                                    const float* __restrict__ sse,
                                                    float* __restrict__ loss,
                                                    float* __restrict__ ppl)
{
    __shared__ int   hist[NE];
    __shared__ float red[NE];
    const int t = threadIdx.x;
    hist[t] = 0;
    __syncthreads();
    const float2* idx2 = reinterpret_cast<const float2*>(idxf);
    for (int i = t; i < N_TOK / 2; i += 1024) {
        float2 v = idx2[i];
        atomicAdd(&hist[(int)v.x], 1);
        atomicAdd(&hist[(int)v.y], 1);
    }
    __syncthreads();
    float p = (float)hist[t] * (1.0f / (float)N_TOK);
    red[t] = p * logf(p + 1e-10f);
    __syncthreads();
    for (int s = 512; s > 0; s >>= 1) {
        if (t < s) red[t] += red[t + s];
        __syncthreads();
    }
    if (t == 0) {
        ppl[0]  = expf(-red[0]);
        loss[0] = 0.25f * sse[0] / (float)(N_TOK * DIM);
    }
}

extern "C" void kernel_launch(void* const* d_in, const int* in_sizes, int n_in,
                              void* d_out, int out_size, void* d_ws, size_t ws_size,
                              hipStream_t stream)
{
    const float* z  = (const float*)d_in[0];   // (32,256,32,32)
    const float* ew = (const float*)d_in[1];   // (1024,256)
    float* out = (float*)d_out;

    float* out_idx = out + OFF_IDX;
    float* out_oh  = out + OFF_OH;
    float* out_zq  = out + OFF_ZQ;
    float* out_ppl = out + OFF_PPL;

    // Scratch placement: prefer d_ws (poison fills show ws ~672 MB). Fallback:
    // inside the one_hot output region (overwritten by vq_onehot afterwards).
    // Offsets keep 16B absolute alignment in both paths (oh base = 8 mod 16).
    const size_t need = 1024u + 33554432u + 524288u + 4194304u + 131072u + 4096u;
    const bool big = ws_size >= need && ws_size >= (size_t)48u * 1024u * 1024u;
    char* base = big ? (char*)d_ws : (char*)out_oh;
    const size_t Z1o = big ? 1024u : 8u;
    const size_t E1o = Z1o + 33554432u;
    const size_t CMo = E1o + 524288u;
    const size_t ZNo = CMo + 4194304u;
    const size_t ENo = ZNo + 131072u;

    unsigned short* Z1 = (unsigned short*)(base + Z1o);
    unsigned short* E1 = (unsigned short*)(base + E1o);
    unsigned long long* CM = (unsigned long long*)(base + CMo);
    float* ZN = (float*)(base + ZNo);
    float* EN = (float*)(base + ENo);
    float* SSE = (float*)d_ws;

    vq_prep<<<516, 256, 0, stream>>>(z, ew, Z1, E1, ZN, EN, SSE);
    vq_argmin_mfma<<<2048, 256, 0, stream>>>(Z1, E1, EN, CM);
    vq_rescore<<<2048, 256, 0, stream>>>(z, ew, ZN, EN, CM, out_idx, out_zq, SSE,
                                         big ? out_oh : nullptr);
    if (!big) vq_onehot<<<2048, 256, 0, stream>>>(out_idx, out_oh);
    vq_finalize<<<1, 1024, 0, stream>>>(out_idx, SSE, out, out_ppl);
}